// Round 1
// baseline (1256.797 us; speedup 1.0000x reference)
//
#include <hip/hip_runtime.h>

#define KVOX 30000
#define TP 35
#define NPTS (KVOX * TP)
#define EPSБ 0
#define EPS_BN 1e-5f

// ---- ws layout (float offsets) ----
#define SLOT1_OFF 0            // 64 x 32   (sum16 | sq16)
#define SLOT2_OFF 2048         // 64 x 128  (sum64 | sq64)
#define SLOT3_OFF 10240        // 64 x 256  (sum128 | sq128)
#define PAR_A1 26624
#define PAR_C1 26640
#define PAR_A2 26656
#define PAR_C2 26720
#define PAR_A3 26784
#define PAR_C3 26912
#define STATS_FLOATS 26624     // memset region: slots only (params fully overwritten)
#define M3MAX_OFF 28672
#define M3MIN_OFF (28672 + KVOX * 128)
#define WS_FULL_FLOATS (28672 + 2 * KVOX * 128)

// ---------------------------------------------------------------------------
// S1: BN1 stats — sums of pw1 = x@W1 + b1 over all K*T points
// ---------------------------------------------------------------------------
__global__ __launch_bounds__(256) void k_stats1(const float* __restrict__ x,
                                                const float* __restrict__ W1,
                                                const float* __restrict__ b1,
                                                float* __restrict__ slot1) {
    int tid = threadIdx.x;
    int gid = blockIdx.x * blockDim.x + tid;
    int stride = gridDim.x * blockDim.x;
    float s[16], q[16];
#pragma unroll
    for (int u = 0; u < 16; ++u) { s[u] = 0.f; q[u] = 0.f; }
    for (int p = gid; p < NPTS; p += stride) {
        const float* xp = x + (size_t)p * 7;
        float xv[7];
#pragma unroll
        for (int c = 0; c < 7; ++c) xv[c] = xp[c];
#pragma unroll
        for (int u = 0; u < 16; ++u) {
            float v = b1[u];
#pragma unroll
            for (int c = 0; c < 7; ++c) v = fmaf(xv[c], W1[c * 16 + u], v);
            s[u] += v;
            q[u] = fmaf(v, v, q[u]);
        }
    }
    int lane = tid & 63;
    int wave = tid >> 6;
    int slot = (blockIdx.x * (blockDim.x >> 6) + wave) & 63;
#pragma unroll
    for (int u = 0; u < 16; ++u) {
        float sv = s[u], qv = q[u];
#pragma unroll
        for (int m = 32; m > 0; m >>= 1) {
            sv += __shfl_xor(sv, m, 64);
            qv += __shfl_xor(qv, m, 64);
        }
        if (lane == 0) {
            atomicAdd(&slot1[slot * 32 + u], sv);
            atomicAdd(&slot1[slot * 32 + 16 + u], qv);
        }
    }
}

// ---------------------------------------------------------------------------
// Generic BN affine finalize: a = g*rsqrt(var+eps), c = be - mean*a
// slots layout: [64][2*C]  (sumC | sqC)
// ---------------------------------------------------------------------------
__global__ void k_affine(const float* __restrict__ slots,
                         const float* __restrict__ g,
                         const float* __restrict__ be,
                         float* __restrict__ pa, float* __restrict__ pc,
                         int C, float invN) {
    int u = threadIdx.x;
    if (u >= C) return;
    float s = 0.f, q = 0.f;
    for (int sl = 0; sl < 64; ++sl) {
        s += slots[sl * 2 * C + u];
        q += slots[sl * 2 * C + C + u];
    }
    float mean = s * invN;
    float var = q * invN - mean * mean;
    float av = g[u] * rsqrtf(var + EPS_BN);
    pa[u] = av;
    pc[u] = be[u] - mean * av;
}

// ---------------------------------------------------------------------------
// Shared phase A: stage-1 VFE for 2 voxels -> masked h1 [2][35][36] in LDS
// h1[...][u<16] = relu(bn1(pw1)) * mask ; h1[...][16+u] = agg1 * mask
// ---------------------------------------------------------------------------
__device__ __forceinline__ void stage1_phaseA(
    int k0, int tid,
    const float* __restrict__ x,
    const float* __restrict__ W1,
    const float* __restrict__ b1,
    const float* __restrict__ a1, const float* __restrict__ c1,
    float* __restrict__ h1,     // [2*35*36]
    float* __restrict__ lmask,  // [70]
    float* __restrict__ agg1) { // [32]
    int u = tid & 15;
    int g = tid >> 4;   // 0..15
    int v = g & 1;
    int th = g >> 1;    // 0..7 (th==7 idle)
#pragma unroll 1
    for (int i = 0; i < 5; ++i) {
        int t = th * 5 + i;
        if (t >= TP) break;
        const float* xp = x + ((size_t)(k0 + v) * TP + t) * 7;
        float xv[7];
        float sum7 = 0.f;
#pragma unroll
        for (int c = 0; c < 7; ++c) { xv[c] = xp[c]; sum7 += xv[c]; }
        if (u == 0) lmask[v * TP + t] = (sum7 != 0.f) ? 1.f : 0.f;
        float val = b1[u];
#pragma unroll
        for (int c = 0; c < 7; ++c) val = fmaf(xv[c], W1[c * 16 + u], val);
        val = fmaxf(a1[u] * val + c1[u], 0.f);       // relu(bn1) — unmasked
        h1[(v * TP + t) * 36 + u] = val;
    }
    __syncthreads();
    if (tid < 32) {
        int vv = tid >> 4, uu = tid & 15;
        float m = 0.f;  // relu output >= 0
        for (int t = 0; t < TP; ++t) m = fmaxf(m, h1[(vv * TP + t) * 36 + uu]);
        agg1[vv * 16 + uu] = m;
    }
    __syncthreads();
    for (int idx = tid; idx < 2 * TP * 32; idx += 256) {
        int vv = idx / (TP * 32);
        int r = idx - vv * (TP * 32);
        int t = r >> 5;
        int uu = r & 31;
        float mk = lmask[vv * TP + t];
        float val = (uu < 16) ? h1[(vv * TP + t) * 36 + uu] : agg1[vv * 16 + (uu - 16)];
        h1[(vv * TP + t) * 36 + uu] = val * mk;
    }
    __syncthreads();
}

// ---------------------------------------------------------------------------
// S2: BN2 stats — sums of pw2 = h1@W2 + b2 (pre-activation) over all points
// block = 2 voxels, 256 threads
// ---------------------------------------------------------------------------
__global__ __launch_bounds__(256) void k_stats2(
    const float* __restrict__ x,
    const float* __restrict__ W1, const float* __restrict__ b1,
    const float* __restrict__ W2, const float* __restrict__ b2,
    const float* __restrict__ ws,
    float* __restrict__ slot2) {
    __shared__ float h1[2 * TP * 36];
    __shared__ float lmask[2 * TP];
    __shared__ float agg1[32];
    __shared__ float redS[256], redQ[256];
    int tid = threadIdx.x;
    int k0 = blockIdx.x * 2;
    int u = tid & 63;
    float w2c[32];
#pragma unroll
    for (int c = 0; c < 32; ++c) w2c[c] = W2[c * 64 + u];

    stage1_phaseA(k0, tid, x, W1, b1, ws + PAR_A1, ws + PAR_C1, h1, lmask, agg1);

    int grp = tid >> 6;
    int v = grp & 1;
    int half = grp >> 1;
    int t0 = half ? 18 : 0;
    int t1 = half ? TP : 18;
    float b2u = b2[u];
    float s = 0.f, q = 0.f;
    for (int t = t0; t < t1; ++t) {
        const float* row = &h1[(v * TP + t) * 36];
        float val = b2u;
#pragma unroll
        for (int c = 0; c < 32; ++c) val = fmaf(row[c], w2c[c], val);
        s += val;
        q = fmaf(val, val, q);
    }
    redS[tid] = s;
    redQ[tid] = q;
    __syncthreads();
    if (tid < 64) {
        float sv = redS[tid] + redS[tid + 64] + redS[tid + 128] + redS[tid + 192];
        float qv = redQ[tid] + redQ[tid + 64] + redQ[tid + 128] + redQ[tid + 192];
        int slot = blockIdx.x & 63;
        atomicAdd(&slot2[slot * 128 + tid], sv);
        atomicAdd(&slot2[slot * 128 + 64 + tid], qv);
    }
}

// ---------------------------------------------------------------------------
// S3: the heavy pass. Per block: 2 voxels.
//  A) stage-1 -> h1 (LDS)
//  B) stage-2: pw2n = relu(bn2(h1@W2+b2)) -> h2T [2][128][36] transposed LDS
//     agg2 + mask -> full masked h2 (concat in channel dim)
//  C) pw3 = h2@Wd (+bd): thread owns column u, acc[35] in regs.
//     Emits per-voxel max/min of raw pw3 + global sum/sq (slotted atomics).
// ---------------------------------------------------------------------------
template <bool WSPATH>
__global__ __launch_bounds__(256) void k_stage3(
    const float* __restrict__ x,
    const float* __restrict__ W1, const float* __restrict__ b1,
    const float* __restrict__ W2, const float* __restrict__ b2,
    const float* __restrict__ Wd, const float* __restrict__ bd,
    const float* __restrict__ ws,
    float* __restrict__ slot3,
    float* __restrict__ m3max, float* __restrict__ m3min,
    float* __restrict__ outbuf) {
    __shared__ float h1[2 * TP * 36];
    __shared__ float h2T[2 * 128 * 36];
    __shared__ float lmask[2 * TP];
    __shared__ float agg1[32];
    __shared__ float agg2[128];
    __shared__ float redS[256], redQ[256];
    int tid = threadIdx.x;
    int k0 = blockIdx.x * 2;
    {
        int u = tid & 63;
        float w2c[32];
#pragma unroll
        for (int c = 0; c < 32; ++c) w2c[c] = W2[c * 64 + u];

        stage1_phaseA(k0, tid, x, W1, b1, ws + PAR_A1, ws + PAR_C1, h1, lmask, agg1);

        int grp = tid >> 6;
        int v = grp & 1;
        int half = grp >> 1;
        int t0 = half ? 18 : 0;
        int t1 = half ? TP : 18;
        float b2u = b2[u];
        float a2u = (ws + PAR_A2)[u];
        float c2u = (ws + PAR_C2)[u];
        for (int t = t0; t < t1; ++t) {
            const float* row = &h1[(v * TP + t) * 36];
            float val = b2u;
#pragma unroll
            for (int c = 0; c < 32; ++c) val = fmaf(row[c], w2c[c], val);
            val = fmaxf(a2u * val + c2u, 0.f);           // relu(bn2) — unmasked
            h2T[((v * 128) + u) * 36 + t] = val;
        }
    }
    __syncthreads();
    if (tid < 128) {
        int v = tid >> 6, uu = tid & 63;
        const float* row = &h2T[(v * 128 + uu) * 36];
        float m = 0.f;
        for (int t = 0; t < TP; ++t) m = fmaxf(m, row[t]);
        agg2[v * 64 + uu] = m;
    }
    __syncthreads();
    for (int idx = tid; idx < 2 * 128 * TP; idx += 256) {
        int v = idx / (128 * TP);
        int r = idx - v * (128 * TP);
        int c = r / TP;
        int t = r - c * TP;
        float mk = lmask[v * TP + t];
        float* p = &h2T[(v * 128 + c) * 36 + t];
        float val = (c < 64) ? (*p) : agg2[v * 64 + (c - 64)];
        *p = val * mk;
    }
    __syncthreads();
    // phase C
    {
        int u = tid & 127;
        int v = tid >> 7;
        float acc[36];
#pragma unroll
        for (int t = 0; t < 36; ++t) acc[t] = 0.f;
        const float* base = &h2T[(v * 128) * 36];
#pragma unroll 1
        for (int c = 0; c < 128; ++c) {
            float wv = Wd[c * 128 + u];
            const float4* r4 = (const float4*)(base + c * 36);
#pragma unroll
            for (int j = 0; j < 9; ++j) {
                float4 qv = r4[j];
                acc[j * 4 + 0] = fmaf(qv.x, wv, acc[j * 4 + 0]);
                acc[j * 4 + 1] = fmaf(qv.y, wv, acc[j * 4 + 1]);
                acc[j * 4 + 2] = fmaf(qv.z, wv, acc[j * 4 + 2]);
                acc[j * 4 + 3] = fmaf(qv.w, wv, acc[j * 4 + 3]);
            }
        }
        float bdu = bd[u];
        float mx = -1e30f, mn = 1e30f, s = 0.f, q = 0.f;
#pragma unroll
        for (int t = 0; t < TP; ++t) {
            float p = acc[t] + bdu;
            mx = fmaxf(mx, p);
            mn = fminf(mn, p);
            s += p;
            q = fmaf(p, p, q);
        }
        int k = k0 + v;
        if (WSPATH) {
            m3max[(size_t)k * 128 + u] = mx;
            m3min[(size_t)k * 128 + u] = mn;
        } else {
            outbuf[(size_t)u * KVOX + k] = mx;
        }
        redS[tid] = s;
        redQ[tid] = q;
    }
    __syncthreads();
    if (tid < 128) {
        float sv = redS[tid] + redS[tid + 128];
        float qv = redQ[tid] + redQ[tid + 128];
        int slot = blockIdx.x & 63;
        atomicAdd(&slot3[slot * 256 + tid], sv);
        atomicAdd(&slot3[slot * 256 + 128 + tid], qv);
    }
}

// ---------------------------------------------------------------------------
// Finalize (ws path): out[u][k] = leaky(bn3(M3sel[k][u])) with LDS transpose
// ---------------------------------------------------------------------------
__global__ __launch_bounds__(256) void k_final_ws(const float* __restrict__ m3max,
                                                  const float* __restrict__ m3min,
                                                  const float* __restrict__ ws,
                                                  float* __restrict__ out) {
    __shared__ float tile[32][33];
    int tx = threadIdx.x & 31;
    int ty = threadIdx.x >> 5;  // 0..7
    int v0 = blockIdx.x * 32;
    int u0 = blockIdx.y * 32;
    const float* a3 = ws + PAR_A3;
    const float* c3 = ws + PAR_C3;
#pragma unroll
    for (int r = ty; r < 32; r += 8) {
        int v = v0 + r, u = u0 + tx;
        float y = 0.f;
        if (v < KVOX) {
            float a = a3[u], c = c3[u];
            float val = (a >= 0.f) ? m3max[(size_t)v * 128 + u] : m3min[(size_t)v * 128 + u];
            y = a * val + c;
            y = (y >= 0.f) ? y : 0.1f * y;
        }
        tile[r][tx] = y;
    }
    __syncthreads();
#pragma unroll
    for (int r = ty; r < 32; r += 8) {
        int u = u0 + r, v = v0 + tx;
        if (v < KVOX) out[(size_t)u * KVOX + v] = tile[tx][r];
    }
}

// Finalize (scatter path): in-place transform of raw maxes living in d_out
__global__ __launch_bounds__(256) void k_final_inplace(const float* __restrict__ ws,
                                                       float* __restrict__ out) {
    int v = blockIdx.x * 256 + threadIdx.x;
    int u = blockIdx.y;
    if (v >= KVOX) return;
    float a = ws[PAR_A3 + u], c = ws[PAR_C3 + u];
    size_t idx = (size_t)u * KVOX + v;
    float y = a * out[idx] + c;
    out[idx] = (y >= 0.f) ? y : 0.1f * y;
}

// ---------------------------------------------------------------------------
extern "C" void kernel_launch(void* const* d_in, const int* in_sizes, int n_in,
                              void* d_out, int out_size, void* d_ws, size_t ws_size,
                              hipStream_t stream) {
    const float* x   = (const float*)d_in[0];
    const void*  coord = d_in[1];
    const float* W1  = (const float*)d_in[3];
    const float* b1  = (const float*)d_in[4];
    const float* g1  = (const float*)d_in[5];
    const float* be1 = (const float*)d_in[6];
    const float* W2  = (const float*)d_in[7];
    const float* b2  = (const float*)d_in[8];
    const float* g2  = (const float*)d_in[9];
    const float* be2 = (const float*)d_in[10];
    const float* Wd  = (const float*)d_in[11];
    const float* bd  = (const float*)d_in[12];
    const float* gd  = (const float*)d_in[13];
    const float* bed = (const float*)d_in[14];
    float* ws = (float*)d_ws;
    float* out = (float*)d_out;

    bool full = ws_size >= (size_t)WS_FULL_FLOATS * 4;
    const float invN = 1.f / (float)NPTS;

    hipMemsetAsync(d_ws, 0, (size_t)STATS_FLOATS * 4, stream);

    k_stats1<<<1024, 256, 0, stream>>>(x, W1, b1, ws + SLOT1_OFF);
    k_affine<<<1, 16, 0, stream>>>(ws + SLOT1_OFF, g1, be1, ws + PAR_A1, ws + PAR_C1, 16, invN);
    k_stats2<<<KVOX / 2, 256, 0, stream>>>(x, W1, b1, W2, b2, ws, ws + SLOT2_OFF);
    k_affine<<<1, 64, 0, stream>>>(ws + SLOT2_OFF, g2, be2, ws + PAR_A2, ws + PAR_C2, 64, invN);
    if (full) {
        k_stage3<true><<<KVOX / 2, 256, 0, stream>>>(x, W1, b1, W2, b2, Wd, bd, ws,
                                                     ws + SLOT3_OFF, ws + M3MAX_OFF,
                                                     ws + M3MIN_OFF, out);
        k_affine<<<1, 128, 0, stream>>>(ws + SLOT3_OFF, gd, bed, ws + PAR_A3, ws + PAR_C3, 128, invN);
        k_final_ws<<<dim3((KVOX + 31) / 32, 4), 256, 0, stream>>>(ws + M3MAX_OFF, ws + M3MIN_OFF, ws, out);
    } else {
        k_stage3<false><<<KVOX / 2, 256, 0, stream>>>(x, W1, b1, W2, b2, Wd, bd, ws,
                                                      ws + SLOT3_OFF, ws, ws, out);
        k_affine<<<1, 128, 0, stream>>>(ws + SLOT3_OFF, gd, bed, ws + PAR_A3, ws + PAR_C3, 128, invN);
        k_final_inplace<<<dim3((KVOX + 255) / 256, 128), 256, 0, stream>>>(ws, out);
    }
    hipMemcpyAsync((char*)d_out + (size_t)128 * KVOX * 4, coord,
                   (size_t)KVOX * 4 * sizeof(int), hipMemcpyDeviceToDevice, stream);
}

// Round 2
// 387.684 us; speedup vs baseline: 3.2418x; 3.2418x over previous
//
#include <hip/hip_runtime.h>

#define KVOX 30000
#define TP 35
#define NPTS (KVOX * TP)
#define EPS_BN 1e-5f

typedef __attribute__((ext_vector_type(8))) short short8_t;   // 8 x bf16
typedef __attribute__((ext_vector_type(4))) float f32x4;

// ---- ws layout (float offsets) ----
#define SLOT1_OFF 0            // 64 x 32   (sum16 | sq16)
#define SLOT2_OFF 2048         // 64 x 128  (sum64 | sq64)
#define SLOT3_OFF 10240        // 64 x 256  (sum128 | sq128)
#define PAR_A1 26624
#define PAR_C1 26640
#define PAR_A2 26656
#define PAR_C2 26720
#define PAR_A3 26784
#define PAR_C3 26912
#define STATS_FLOATS 26624     // memset region: slots only
#define W2T_OFF 27136          // 2048 bf16 = 1024 floats  [64 cols][32 k]
#define WDT_OFF 28160          // 16384 bf16 = 8192 floats [128 cols][128 k]
#define M3MAX_OFF 36864
#define M3MIN_OFF (36864 + KVOX * 128)
#define WS_FULL_FLOATS (36864 + 2 * KVOX * 128)

__device__ __forceinline__ ushort f2bf(float f) {
    union { float f; uint u; } v; v.f = f;
    uint r = v.u + 0x7FFFu + ((v.u >> 16) & 1u);
    return (ushort)(r >> 16);
}
__device__ __forceinline__ float bf2f(ushort h) {
    union { uint u; float f; } v; v.u = ((uint)h) << 16; return v.f;
}

// ---------------------------------------------------------------------------
// prep: transpose W2 (32x64) and Wd (128x128) into bf16 [col][k] in ws
// ---------------------------------------------------------------------------
__global__ __launch_bounds__(256) void k_prep(const float* __restrict__ W2,
                                              const float* __restrict__ Wd,
                                              ushort* __restrict__ w2t,
                                              ushort* __restrict__ wdt) {
    int tid = blockIdx.x * 256 + threadIdx.x;   // 0..16383
    if (tid < 2048) {
        int u = tid >> 5, k = tid & 31;
        w2t[tid] = f2bf(W2[k * 64 + u]);
    }
    int u = tid >> 7, k = tid & 127;
    wdt[tid] = f2bf(Wd[k * 128 + u]);
}

// ---------------------------------------------------------------------------
// S1: BN1 stats
// ---------------------------------------------------------------------------
__global__ __launch_bounds__(256) void k_stats1(const float* __restrict__ x,
                                                const float* __restrict__ W1,
                                                const float* __restrict__ b1,
                                                float* __restrict__ slot1) {
    int tid = threadIdx.x;
    int gid = blockIdx.x * blockDim.x + tid;
    int stride = gridDim.x * blockDim.x;
    float s[16], q[16];
#pragma unroll
    for (int u = 0; u < 16; ++u) { s[u] = 0.f; q[u] = 0.f; }
    for (int p = gid; p < NPTS; p += stride) {
        const float* xp = x + (size_t)p * 7;
        float xv[7];
#pragma unroll
        for (int c = 0; c < 7; ++c) xv[c] = xp[c];
#pragma unroll
        for (int u = 0; u < 16; ++u) {
            float v = b1[u];
#pragma unroll
            for (int c = 0; c < 7; ++c) v = fmaf(xv[c], W1[c * 16 + u], v);
            s[u] += v;
            q[u] = fmaf(v, v, q[u]);
        }
    }
    int lane = tid & 63;
    int wave = tid >> 6;
    int slot = (blockIdx.x * (blockDim.x >> 6) + wave) & 63;
#pragma unroll
    for (int u = 0; u < 16; ++u) {
        float sv = s[u], qv = q[u];
#pragma unroll
        for (int m = 32; m > 0; m >>= 1) {
            sv += __shfl_xor(sv, m, 64);
            qv += __shfl_xor(qv, m, 64);
        }
        if (lane == 0) {
            atomicAdd(&slot1[slot * 32 + u], sv);
            atomicAdd(&slot1[slot * 32 + 16 + u], qv);
        }
    }
}

// ---------------------------------------------------------------------------
// BN affine finalize
// ---------------------------------------------------------------------------
__global__ void k_affine(const float* __restrict__ slots,
                         const float* __restrict__ g,
                         const float* __restrict__ be,
                         float* __restrict__ pa, float* __restrict__ pc,
                         int C, float invN) {
    int u = threadIdx.x;
    if (u >= C) return;
    float s = 0.f, q = 0.f;
    for (int sl = 0; sl < 64; ++sl) {
        s += slots[sl * 2 * C + u];
        q += slots[sl * 2 * C + C + u];
    }
    float mean = s * invN;
    float var = q * invN - mean * mean;
    float av = g[u] * rsqrtf(var + EPS_BN);
    pa[u] = av;
    pc[u] = be[u] - mean * av;
}

// ---------------------------------------------------------------------------
// fp32 phase A (used by k_stats2 only): h1 [2][35][36] masked fp32
// ---------------------------------------------------------------------------
__device__ __forceinline__ void stage1_phaseA_f32(
    int k0, int tid,
    const float* __restrict__ x,
    const float* __restrict__ W1,
    const float* __restrict__ b1,
    const float* __restrict__ a1, const float* __restrict__ c1,
    float* __restrict__ h1, float* __restrict__ lmask, float* __restrict__ agg1) {
    int u = tid & 15;
    int g = tid >> 4;
    int v = g & 1;
    int th = g >> 1;
#pragma unroll 1
    for (int i = 0; i < 5; ++i) {
        int t = th * 5 + i;
        if (t >= TP) break;
        const float* xp = x + ((size_t)(k0 + v) * TP + t) * 7;
        float xv[7];
        float sum7 = 0.f;
#pragma unroll
        for (int c = 0; c < 7; ++c) { xv[c] = xp[c]; sum7 += xv[c]; }
        if (u == 0) lmask[v * TP + t] = (sum7 != 0.f) ? 1.f : 0.f;
        float val = b1[u];
#pragma unroll
        for (int c = 0; c < 7; ++c) val = fmaf(xv[c], W1[c * 16 + u], val);
        val = fmaxf(a1[u] * val + c1[u], 0.f);
        h1[(v * TP + t) * 36 + u] = val;
    }
    __syncthreads();
    if (tid < 32) {
        int vv = tid >> 4, uu = tid & 15;
        float m = 0.f;
        for (int t = 0; t < TP; ++t) m = fmaxf(m, h1[(vv * TP + t) * 36 + uu]);
        agg1[vv * 16 + uu] = m;
    }
    __syncthreads();
    for (int idx = tid; idx < 2 * TP * 32; idx += 256) {
        int vv = idx / (TP * 32);
        int r = idx - vv * (TP * 32);
        int t = r >> 5;
        int uu = r & 31;
        float mk = lmask[vv * TP + t];
        float val = (uu < 16) ? h1[(vv * TP + t) * 36 + uu] : agg1[vv * 16 + (uu - 16)];
        h1[(vv * TP + t) * 36 + uu] = val * mk;
    }
    __syncthreads();
}

// ---------------------------------------------------------------------------
// S2: BN2 stats (exact fp32 path)
// ---------------------------------------------------------------------------
__global__ __launch_bounds__(256) void k_stats2(
    const float* __restrict__ x,
    const float* __restrict__ W1, const float* __restrict__ b1,
    const float* __restrict__ W2, const float* __restrict__ b2,
    const float* __restrict__ ws,
    float* __restrict__ slot2) {
    __shared__ float h1[2 * TP * 36];
    __shared__ float lmask[2 * TP];
    __shared__ float agg1[32];
    __shared__ float redS[256], redQ[256];
    int tid = threadIdx.x;
    int k0 = blockIdx.x * 2;
    int u = tid & 63;
    float w2c[32];
#pragma unroll
    for (int c = 0; c < 32; ++c) w2c[c] = W2[c * 64 + u];

    stage1_phaseA_f32(k0, tid, x, W1, b1, ws + PAR_A1, ws + PAR_C1, h1, lmask, agg1);

    int grp = tid >> 6;
    int v = grp & 1;
    int half = grp >> 1;
    int t0 = half ? 18 : 0;
    int t1 = half ? TP : 18;
    float b2u = b2[u];
    float s = 0.f, q = 0.f;
    for (int t = t0; t < t1; ++t) {
        const float* row = &h1[(v * TP + t) * 36];
        float val = b2u;
#pragma unroll
        for (int c = 0; c < 32; ++c) val = fmaf(row[c], w2c[c], val);
        s += val;
        q = fmaf(val, val, q);
    }
    redS[tid] = s;
    redQ[tid] = q;
    __syncthreads();
    if (tid < 64) {
        float sv = redS[tid] + redS[tid + 64] + redS[tid + 128] + redS[tid + 192];
        float qv = redQ[tid] + redQ[tid + 64] + redQ[tid + 128] + redQ[tid + 192];
        int slot = blockIdx.x & 63;
        atomicAdd(&slot2[slot * 128 + tid], sv);
        atomicAdd(&slot2[slot * 128 + 64 + tid], qv);
    }
}

// ---------------------------------------------------------------------------
// S3 heavy pass, MFMA edition. Block = 2 voxels, 256 threads (4 waves).
//  A) stage-1 -> h1 bf16 [80 rows][40] (rows = v*35+t, 70 valid, pad 0)
//  B) MFMA [80x32]@[32x64] -> relu(bn2) -> h2 bf16 [80][136]; agg2+mask
//  C) MFMA [80x128]@[128x128], per-lane epilogue: bias, per-voxel max/min,
//     global sum/sq via slotted atomics.
// ---------------------------------------------------------------------------
template <bool WSPATH>
__global__ __launch_bounds__(256) void k_stage3(
    const float* __restrict__ x,
    const float* __restrict__ W1, const float* __restrict__ b1,
    const float* __restrict__ b2,
    const ushort* __restrict__ w2t, const ushort* __restrict__ wdt,
    const float* __restrict__ bd,
    const float* __restrict__ ws,
    float* __restrict__ slot3,
    float* __restrict__ m3max, float* __restrict__ m3min,
    float* __restrict__ outbuf) {
    __shared__ ushort h1[80 * 40];
    __shared__ ushort h2[80 * 136];
    __shared__ float lmask[2 * TP];
    __shared__ float agg1[32];
    __shared__ float agg2[128];
    int tid = threadIdx.x;
    int k0 = blockIdx.x * 2;
    int w = tid >> 6;        // wave 0..3
    int lane = tid & 63;
    int lq = lane >> 4;      // 0..3
    int lr = lane & 15;      // 0..15

    // ---- phase A: stage 1 ----
    {
        int u = tid & 15;
        int g = tid >> 4;
        int v = g & 1;
        int th = g >> 1;
#pragma unroll 1
        for (int i = 0; i < 5; ++i) {
            int t = th * 5 + i;
            if (t >= TP) break;
            const float* xp = x + ((size_t)(k0 + v) * TP + t) * 7;
            float xv[7];
            float sum7 = 0.f;
#pragma unroll
            for (int c = 0; c < 7; ++c) { xv[c] = xp[c]; sum7 += xv[c]; }
            if (u == 0) lmask[v * TP + t] = (sum7 != 0.f) ? 1.f : 0.f;
            float val = b1[u];
#pragma unroll
            for (int c = 0; c < 7; ++c) val = fmaf(xv[c], W1[c * 16 + u], val);
            val = fmaxf((ws + PAR_A1)[u] * val + (ws + PAR_C1)[u], 0.f);
            h1[(v * TP + t) * 40 + u] = f2bf(val);
        }
    }
    __syncthreads();
    if (tid < 32) {
        int vv = tid >> 4, uu = tid & 15;
        float m = 0.f;
        for (int t = 0; t < TP; ++t) m = fmaxf(m, bf2f(h1[(vv * TP + t) * 40 + uu]));
        agg1[tid] = m;
    }
    __syncthreads();
    for (int idx = tid; idx < 80 * 32; idx += 256) {
        int row = idx >> 5;
        int uu = idx & 31;
        float val = 0.f;
        if (row < 70) {
            int v = row >= TP;
            float base = (uu < 16) ? bf2f(h1[row * 40 + uu]) : agg1[v * 16 + (uu - 16)];
            val = base * lmask[row];
        }
        h1[row * 40 + uu] = f2bf(val);
    }
    __syncthreads();

    // ---- phase B: stage 2 via MFMA; wave w owns N-tile w (u = w*16+lr) ----
    {
        int u = w * 16 + lr;
        short8_t bfrag = *(const short8_t*)(w2t + (u * 32 + lq * 8));
        float b2u = b2[u];
        float a2u = (ws + PAR_A2)[u];
        float c2u = (ws + PAR_C2)[u];
#pragma unroll
        for (int mt = 0; mt < 5; ++mt) {
            short8_t afrag = *(const short8_t*)(&h1[(mt * 16 + lr) * 40 + lq * 8]);
            f32x4 acc = {0.f, 0.f, 0.f, 0.f};
            acc = __builtin_amdgcn_mfma_f32_16x16x32_bf16(afrag, bfrag, acc, 0, 0, 0);
#pragma unroll
            for (int r = 0; r < 4; ++r) {
                int m = mt * 16 + lq * 4 + r;
                float pw = acc[r] + b2u;
                float val = fmaxf(a2u * pw + c2u, 0.f);
                h2[m * 136 + u] = f2bf(val);
            }
        }
    }
    __syncthreads();
    if (tid < 128) {
        int v = tid >> 6, uu = tid & 63;
        float m = 0.f;
        for (int t = 0; t < TP; ++t) m = fmaxf(m, bf2f(h2[(v * TP + t) * 136 + uu]));
        agg2[tid] = m;
    }
    __syncthreads();
    for (int idx = tid; idx < 80 * 128; idx += 256) {
        int row = idx >> 7;
        int c = idx & 127;
        float val = 0.f;
        if (row < 70) {
            int v = row >= TP;
            float base = (c < 64) ? bf2f(h2[row * 136 + c]) : agg2[v * 64 + (c - 64)];
            val = base * lmask[row];
        }
        h2[row * 136 + c] = f2bf(val);
    }
    __syncthreads();

    // ---- phase C: stage 3 via MFMA; wave w owns N-tiles {2w, 2w+1} ----
    {
        int u0 = w * 32;
        short8_t bfr[2][4];
#pragma unroll
        for (int s = 0; s < 2; ++s)
#pragma unroll
            for (int kk = 0; kk < 4; ++kk)
                bfr[s][kk] = *(const short8_t*)(wdt + ((u0 + s * 16 + lr) * 128 + kk * 32 + lq * 8));
        float bdv[2] = { bd[u0 + lr], bd[u0 + 16 + lr] };
        float mx[2][2], mn[2][2], sm[2], sq[2];
#pragma unroll
        for (int s = 0; s < 2; ++s) {
            sm[s] = 0.f; sq[s] = 0.f;
#pragma unroll
            for (int v = 0; v < 2; ++v) { mx[s][v] = -1e30f; mn[s][v] = 1e30f; }
        }
#pragma unroll
        for (int mt = 0; mt < 5; ++mt) {
            short8_t af[4];
#pragma unroll
            for (int kk = 0; kk < 4; ++kk)
                af[kk] = *(const short8_t*)(&h2[(mt * 16 + lr) * 136 + kk * 32 + lq * 8]);
#pragma unroll
            for (int s = 0; s < 2; ++s) {
                f32x4 acc = {0.f, 0.f, 0.f, 0.f};
#pragma unroll
                for (int kk = 0; kk < 4; ++kk)
                    acc = __builtin_amdgcn_mfma_f32_16x16x32_bf16(af[kk], bfr[s][kk], acc, 0, 0, 0);
#pragma unroll
                for (int r = 0; r < 4; ++r) {
                    int m = mt * 16 + lq * 4 + r;
                    if (m < 70) {
                        int v = m >= TP;
                        float p = acc[r] + bdv[s];
                        mx[s][v] = fmaxf(mx[s][v], p);
                        mn[s][v] = fminf(mn[s][v], p);
                        sm[s] += p;
                        sq[s] = fmaf(p, p, sq[s]);
                    }
                }
            }
        }
        // cross-lane (lq) reduction: lanes lane^16, lane^32 share the same u
#pragma unroll
        for (int s = 0; s < 2; ++s) {
#pragma unroll
            for (int v = 0; v < 2; ++v) {
                mx[s][v] = fmaxf(mx[s][v], __shfl_xor(mx[s][v], 16, 64));
                mx[s][v] = fmaxf(mx[s][v], __shfl_xor(mx[s][v], 32, 64));
                mn[s][v] = fminf(mn[s][v], __shfl_xor(mn[s][v], 16, 64));
                mn[s][v] = fminf(mn[s][v], __shfl_xor(mn[s][v], 32, 64));
            }
            sm[s] += __shfl_xor(sm[s], 16, 64);
            sm[s] += __shfl_xor(sm[s], 32, 64);
            sq[s] += __shfl_xor(sq[s], 16, 64);
            sq[s] += __shfl_xor(sq[s], 32, 64);
        }
        if (lq == 0) {
            int slot = blockIdx.x & 63;
#pragma unroll
            for (int s = 0; s < 2; ++s) {
                int u = u0 + s * 16 + lr;
                if (WSPATH) {
#pragma unroll
                    for (int v = 0; v < 2; ++v) {
                        m3max[(size_t)(k0 + v) * 128 + u] = mx[s][v];
                        m3min[(size_t)(k0 + v) * 128 + u] = mn[s][v];
                    }
                } else {
#pragma unroll
                    for (int v = 0; v < 2; ++v)
                        outbuf[(size_t)u * KVOX + (k0 + v)] = mx[s][v];
                }
                atomicAdd(&slot3[slot * 256 + u], sm[s]);
                atomicAdd(&slot3[slot * 256 + 128 + u], sq[s]);
            }
        }
    }
}

// ---------------------------------------------------------------------------
// Finalize (ws path): out[u][k] = leaky(bn3(M3sel[k][u])) with LDS transpose
// ---------------------------------------------------------------------------
__global__ __launch_bounds__(256) void k_final_ws(const float* __restrict__ m3max,
                                                  const float* __restrict__ m3min,
                                                  const float* __restrict__ ws,
                                                  float* __restrict__ out) {
    __shared__ float tile[32][33];
    int tx = threadIdx.x & 31;
    int ty = threadIdx.x >> 5;
    int v0 = blockIdx.x * 32;
    int u0 = blockIdx.y * 32;
    const float* a3 = ws + PAR_A3;
    const float* c3 = ws + PAR_C3;
#pragma unroll
    for (int r = ty; r < 32; r += 8) {
        int v = v0 + r, u = u0 + tx;
        float y = 0.f;
        if (v < KVOX) {
            float a = a3[u], c = c3[u];
            float val = (a >= 0.f) ? m3max[(size_t)v * 128 + u] : m3min[(size_t)v * 128 + u];
            y = a * val + c;
            y = (y >= 0.f) ? y : 0.1f * y;
        }
        tile[r][tx] = y;
    }
    __syncthreads();
#pragma unroll
    for (int r = ty; r < 32; r += 8) {
        int u = u0 + r, v = v0 + tx;
        if (v < KVOX) out[(size_t)u * KVOX + v] = tile[tx][r];
    }
}

__global__ __launch_bounds__(256) void k_final_inplace(const float* __restrict__ ws,
                                                       float* __restrict__ out) {
    int v = blockIdx.x * 256 + threadIdx.x;
    int u = blockIdx.y;
    if (v >= KVOX) return;
    float a = ws[PAR_A3 + u], c = ws[PAR_C3 + u];
    size_t idx = (size_t)u * KVOX + v;
    float y = a * out[idx] + c;
    out[idx] = (y >= 0.f) ? y : 0.1f * y;
}

// ---------------------------------------------------------------------------
extern "C" void kernel_launch(void* const* d_in, const int* in_sizes, int n_in,
                              void* d_out, int out_size, void* d_ws, size_t ws_size,
                              hipStream_t stream) {
    const float* x   = (const float*)d_in[0];
    const void*  coord = d_in[1];
    const float* W1  = (const float*)d_in[3];
    const float* b1  = (const float*)d_in[4];
    const float* g1  = (const float*)d_in[5];
    const float* be1 = (const float*)d_in[6];
    const float* W2  = (const float*)d_in[7];
    const float* b2  = (const float*)d_in[8];
    const float* g2  = (const float*)d_in[9];
    const float* be2 = (const float*)d_in[10];
    const float* Wd  = (const float*)d_in[11];
    const float* bd  = (const float*)d_in[12];
    const float* gd  = (const float*)d_in[13];
    const float* bed = (const float*)d_in[14];
    float* ws = (float*)d_ws;
    float* out = (float*)d_out;
    ushort* w2t = (ushort*)(ws + W2T_OFF);
    ushort* wdt = (ushort*)(ws + WDT_OFF);

    bool full = ws_size >= (size_t)WS_FULL_FLOATS * 4;
    const float invN = 1.f / (float)NPTS;

    hipMemsetAsync(d_ws, 0, (size_t)STATS_FLOATS * 4, stream);

    k_prep<<<64, 256, 0, stream>>>(W2, Wd, w2t, wdt);
    k_stats1<<<1024, 256, 0, stream>>>(x, W1, b1, ws + SLOT1_OFF);
    k_affine<<<1, 16, 0, stream>>>(ws + SLOT1_OFF, g1, be1, ws + PAR_A1, ws + PAR_C1, 16, invN);
    k_stats2<<<KVOX / 2, 256, 0, stream>>>(x, W1, b1, W2, b2, ws, ws + SLOT2_OFF);
    k_affine<<<1, 64, 0, stream>>>(ws + SLOT2_OFF, g2, be2, ws + PAR_A2, ws + PAR_C2, 64, invN);
    if (full) {
        k_stage3<true><<<KVOX / 2, 256, 0, stream>>>(x, W1, b1, b2, w2t, wdt, bd, ws,
                                                     ws + SLOT3_OFF, ws + M3MAX_OFF,
                                                     ws + M3MIN_OFF, out);
        k_affine<<<1, 128, 0, stream>>>(ws + SLOT3_OFF, gd, bed, ws + PAR_A3, ws + PAR_C3, 128, invN);
        k_final_ws<<<dim3((KVOX + 31) / 32, 4), 256, 0, stream>>>(ws + M3MAX_OFF, ws + M3MIN_OFF, ws, out);
    } else {
        k_stage3<false><<<KVOX / 2, 256, 0, stream>>>(x, W1, b1, b2, w2t, wdt, bd, ws,
                                                      ws + SLOT3_OFF, ws, ws, out);
        k_affine<<<1, 128, 0, stream>>>(ws + SLOT3_OFF, gd, bed, ws + PAR_A3, ws + PAR_C3, 128, invN);
        k_final_inplace<<<dim3((KVOX + 255) / 256, 128), 256, 0, stream>>>(ws, out);
    }
    hipMemcpyAsync((char*)d_out + (size_t)128 * KVOX * 4, coord,
                   (size_t)KVOX * 4 * sizeof(int), hipMemcpyDeviceToDevice, stream);
}

// Round 3
// 209.093 us; speedup vs baseline: 6.0107x; 1.8541x over previous
//
#include <hip/hip_runtime.h>

#define KVOX 30000
#define TP 35
#define NPTS (KVOX * TP)
#define EPS_BN 1e-5f

typedef __attribute__((ext_vector_type(8))) short short8_t;   // 8 x bf16
typedef __attribute__((ext_vector_type(4))) float f32x4;

// ---- ws layout (float offsets) ----
#define SLOT1_OFF 0            // 64 x 32   (sum16 | sq16)
#define SLOT2_OFF 2048         // 64 x 128  (sum64 | sq64)
#define SLOT3_OFF 10240        // 64 x 256  (sum128 | sq128)
#define PAR_A1 26624
#define PAR_C1 26640
#define PAR_A2 26656
#define PAR_C2 26720
#define PAR_A3 26784
#define PAR_C3 26912
#define STATS_FLOATS 26624     // memset region: slots only
#define W2T_OFF 27136          // [64 u][32 k] bf16
#define WDT_OFF 28160          // [128 u][128 k] bf16
#define M3MAX_OFF 36864
#define M3MIN_OFF (36864 + KVOX * 128)
#define WS_FULL_FLOATS (36864 + 2 * KVOX * 128)

__device__ __forceinline__ ushort f2bf(float f) {
    union { float f; uint u; } v; v.f = f;
    uint r = v.u + 0x7FFFu + ((v.u >> 16) & 1u);
    return (ushort)(r >> 16);
}

// ---------------------------------------------------------------------------
// prep (blocks 0..63): W2T/WDT bf16 transposes. stats1 (blocks 64+): BN1 sums.
// ---------------------------------------------------------------------------
__global__ __launch_bounds__(256) void k_prep_stats1(
    const float* __restrict__ x,
    const float* __restrict__ W1, const float* __restrict__ b1,
    const float* __restrict__ W2, const float* __restrict__ Wd,
    ushort* __restrict__ w2t, ushort* __restrict__ wdt,
    float* __restrict__ slot1) {
    if (blockIdx.x < 64) {
        int tid = blockIdx.x * 256 + threadIdx.x;   // 0..16383
        if (tid < 2048) {
            int u = tid >> 5, k = tid & 31;
            w2t[tid] = f2bf(W2[k * 64 + u]);
        }
        int u = tid >> 7, k = tid & 127;
        wdt[tid] = f2bf(Wd[k * 128 + u]);
        return;
    }
    int bid = blockIdx.x - 64;                      // 0..1023
    int tid = threadIdx.x;
    int gid = bid * 256 + tid;
    int stride = 1024 * 256;
    float s[16], q[16];
#pragma unroll
    for (int u = 0; u < 16; ++u) { s[u] = 0.f; q[u] = 0.f; }
    for (int p = gid; p < NPTS; p += stride) {
        const float* xp = x + (size_t)p * 7;
        float xv[7];
#pragma unroll
        for (int c = 0; c < 7; ++c) xv[c] = xp[c];
#pragma unroll
        for (int u = 0; u < 16; ++u) {
            float v = b1[u];
#pragma unroll
            for (int c = 0; c < 7; ++c) v = fmaf(xv[c], W1[c * 16 + u], v);
            s[u] += v;
            q[u] = fmaf(v, v, q[u]);
        }
    }
    int lane = tid & 63;
    int wave = tid >> 6;
    int slot = (bid * 4 + wave) & 63;
#pragma unroll
    for (int u = 0; u < 16; ++u) {
        float sv = s[u], qv = q[u];
#pragma unroll
        for (int m = 32; m > 0; m >>= 1) {
            sv += __shfl_xor(sv, m, 64);
            qv += __shfl_xor(qv, m, 64);
        }
        if (lane == 0) {
            atomicAdd(&slot1[slot * 32 + u], sv);
            atomicAdd(&slot1[slot * 32 + 16 + u], qv);
        }
    }
}

// ---------------------------------------------------------------------------
// BN affine finalize (no-bias variant, stats include bias)
// ---------------------------------------------------------------------------
__global__ void k_affine(const float* __restrict__ slots,
                         const float* __restrict__ g,
                         const float* __restrict__ be,
                         float* __restrict__ pa, float* __restrict__ pc,
                         int C, float invN) {
    int u = threadIdx.x;
    if (u >= C) return;
    float s = 0.f, q = 0.f;
    for (int sl = 0; sl < 64; ++sl) {
        s += slots[sl * 2 * C + u];
        q += slots[sl * 2 * C + C + u];
    }
    float mean = s * invN;
    float var = q * invN - mean * mean;
    float av = g[u] * rsqrtf(var + EPS_BN);
    pa[u] = av;
    pc[u] = be[u] - mean * av;
}

// Bias-folded variant: slots hold sums of (pw - b); reconstruct moments.
__global__ void k_affine_b(const float* __restrict__ slots,
                           const float* __restrict__ g,
                           const float* __restrict__ be,
                           const float* __restrict__ bias,
                           float* __restrict__ pa, float* __restrict__ pc,
                           int C, float invN) {
    int u = threadIdx.x;
    if (u >= C) return;
    float s = 0.f, q = 0.f;
    for (int sl = 0; sl < 64; ++sl) {
        s += slots[sl * 2 * C + u];
        q += slots[sl * 2 * C + C + u];
    }
    float b = bias[u];
    float mr = s * invN;               // E[acc]
    float mean = mr + b;               // E[pw]
    float ex2 = q * invN + 2.f * b * mr + b * b;  // E[pw^2]
    float var = ex2 - mean * mean;
    float av = g[u] * rsqrtf(var + EPS_BN);
    pa[u] = av;
    pc[u] = be[u] - mean * av;
}

// ---------------------------------------------------------------------------
// Phase A (shared): stage-1 VFE, 2 voxels -> h1 bf16 [80][40] fully masked,
// mask fused at write; agg1 via in-register partials + shfl; rows 70..79 = 0.
// ---------------------------------------------------------------------------
__device__ __forceinline__ void phaseA(
    int k0, int tid,
    const float* __restrict__ x,
    const float* __restrict__ W1, const float* __restrict__ b1,
    const float* __restrict__ a1, const float* __restrict__ c1,
    ushort* __restrict__ h1,     // [80*40]
    float* __restrict__ lmask,   // [80]
    float* __restrict__ aggp) {  // [128] wave partials [w][v*16+u]
    int u = tid & 15;
    int g = tid >> 4;   // 0..15
    int v = g & 1;
    int th = g >> 1;    // 0..7
    float pmax = 0.f;
    if (th < 7) {
        float b1u = b1[u];
        float a1u = a1[u], c1u = c1[u];
        float w1c[7];
#pragma unroll
        for (int c = 0; c < 7; ++c) w1c[c] = W1[c * 16 + u];
#pragma unroll
        for (int i = 0; i < 5; ++i) {
            int t = th * 5 + i;
            const float* xp = x + ((size_t)(k0 + v) * TP + t) * 7;
            float xv[7];
            float sum7 = 0.f;
#pragma unroll
            for (int c = 0; c < 7; ++c) { xv[c] = xp[c]; sum7 += xv[c]; }
            float mk = (sum7 != 0.f) ? 1.f : 0.f;
            if (u == 0) lmask[v * TP + t] = mk;
            float val = b1u;
#pragma unroll
            for (int c = 0; c < 7; ++c) val = fmaf(xv[c], w1c[c], val);
            val = fmaxf(fmaf(a1u, val, c1u), 0.f);
            pmax = fmaxf(pmax, val);                 // unmasked (ref semantics)
            h1[(v * TP + t) * 40 + u] = f2bf(val * mk);
        }
    } else {
        // g==14,15: zero pad rows 70..79 (cols 0..15) + pad lmask
#pragma unroll
        for (int i = 0; i < 5; ++i) {
            int row = 70 + (g & 1) * 5 + i;
            h1[row * 40 + u] = 0;
            if (u == 0) lmask[row] = 0.f;
        }
    }
    // combine th-pairs within wave (lanes ^32 share (v,u), differ in th)
    pmax = fmaxf(pmax, __shfl_xor(pmax, 32, 64));
    int w = tid >> 6;
    int lane = tid & 63;
    if (lane < 32) aggp[w * 32 + lane] = pmax;       // lane = v*16+u
    __syncthreads();
    // fill cols 16..31 for all 80 rows: agg1 (4-way max inline) * mask
    {
        int uu = tid & 15;
        int r0 = tid >> 4;  // 0..15
        float g0 = fmaxf(fmaxf(aggp[uu], aggp[32 + uu]),
                         fmaxf(aggp[64 + uu], aggp[96 + uu]));
        float g1 = fmaxf(fmaxf(aggp[16 + uu], aggp[48 + uu]),
                         fmaxf(aggp[80 + uu], aggp[112 + uu]));
        ushort a0 = f2bf(g0), a1b = f2bf(g1);
#pragma unroll
        for (int j = 0; j < 5; ++j) {
            int row = r0 + j * 16;
            float mk = lmask[row];
            h1[row * 40 + 16 + uu] = (mk != 0.f) ? ((row < TP) ? a0 : a1b) : (ushort)0;
        }
    }
    __syncthreads();
}

// ---------------------------------------------------------------------------
// S2: BN2 stats via MFMA. Sums of acc = pw2 - b2 (bias folded in k_affine_b).
// Pad rows give acc = 0 -> no guard needed.
// ---------------------------------------------------------------------------
__global__ __launch_bounds__(256) void k_stats2(
    const float* __restrict__ x,
    const float* __restrict__ W1, const float* __restrict__ b1,
    const ushort* __restrict__ w2t,
    const float* __restrict__ ws,
    float* __restrict__ slot2) {
    __shared__ ushort h1[80 * 40];
    __shared__ float lmask[80];
    __shared__ float aggp[128];
    int tid = threadIdx.x;
    int k0 = blockIdx.x * 2;
    phaseA(k0, tid, x, W1, b1, ws + PAR_A1, ws + PAR_C1, h1, lmask, aggp);
    int w = tid >> 6, lane = tid & 63, lq = lane >> 4, lr = lane & 15;
    int u = w * 16 + lr;
    short8_t bfrag = *(const short8_t*)(w2t + u * 32 + lq * 8);
    float s1v = 0.f, s2v = 0.f;
#pragma unroll
    for (int mt = 0; mt < 5; ++mt) {
        short8_t afrag = *(const short8_t*)(h1 + (mt * 16 + lr) * 40 + lq * 8);
        f32x4 acc = {0.f, 0.f, 0.f, 0.f};
        acc = __builtin_amdgcn_mfma_f32_16x16x32_bf16(afrag, bfrag, acc, 0, 0, 0);
#pragma unroll
        for (int r = 0; r < 4; ++r) { s1v += acc[r]; s2v = fmaf(acc[r], acc[r], s2v); }
    }
    s1v += __shfl_xor(s1v, 16, 64); s1v += __shfl_xor(s1v, 32, 64);
    s2v += __shfl_xor(s2v, 16, 64); s2v += __shfl_xor(s2v, 32, 64);
    if (lq == 0) {
        int slot = blockIdx.x & 63;
        atomicAdd(&slot2[slot * 128 + u], s1v);
        atomicAdd(&slot2[slot * 128 + 64 + u], s2v);
    }
}

// ---------------------------------------------------------------------------
// S3 heavy pass. Fused masks, in-register agg2, bias-folded epilogue stats.
// ---------------------------------------------------------------------------
template <bool WSPATH>
__global__ __launch_bounds__(256) void k_stage3(
    const float* __restrict__ x,
    const float* __restrict__ W1, const float* __restrict__ b1,
    const float* __restrict__ b2,
    const ushort* __restrict__ w2t, const ushort* __restrict__ wdt,
    const float* __restrict__ bd, const float* __restrict__ gd,
    const float* __restrict__ ws,
    float* __restrict__ slot3,
    float* __restrict__ m3max, float* __restrict__ m3min,
    float* __restrict__ outbuf) {
    __shared__ ushort h1[80 * 40];
    __shared__ ushort h2[80 * 136];
    __shared__ float lmask[80];
    __shared__ float aggp[128];
    __shared__ ushort agg2bf[128];
    int tid = threadIdx.x;
    int k0 = blockIdx.x * 2;
    int w = tid >> 6, lane = tid & 63, lq = lane >> 4, lr = lane & 15;

    phaseA(k0, tid, x, W1, b1, ws + PAR_A1, ws + PAR_C1, h1, lmask, aggp);

    // prefetch Wd fragments (cover latency with phase B)
    int u0 = w * 32;
    short8_t bfr[2][4];
#pragma unroll
    for (int s = 0; s < 2; ++s)
#pragma unroll
        for (int kk = 0; kk < 4; ++kk)
            bfr[s][kk] = *(const short8_t*)(wdt + ((u0 + s * 16 + lr) * 128 + kk * 32 + lq * 8));

    // ---- phase B: h2 cols 0..63 (masked at write) + in-register agg2 ----
    {
        int u = w * 16 + lr;
        short8_t bfrag = *(const short8_t*)(w2t + u * 32 + lq * 8);
        float a2u = (ws + PAR_A2)[u];
        float c2p = fmaf(a2u, b2[u], (ws + PAR_C2)[u]);   // a2*b2 + c2
        float aggv0 = 0.f, aggv1 = 0.f;
#pragma unroll
        for (int mt = 0; mt < 5; ++mt) {
            short8_t afrag = *(const short8_t*)(h1 + (mt * 16 + lr) * 40 + lq * 8);
            f32x4 acc = {0.f, 0.f, 0.f, 0.f};
            acc = __builtin_amdgcn_mfma_f32_16x16x32_bf16(afrag, bfrag, acc, 0, 0, 0);
#pragma unroll
            for (int r = 0; r < 4; ++r) {
                int m = mt * 16 + lq * 4 + r;
                float val = fmaxf(fmaf(a2u, acc[r], c2p), 0.f);
                if (mt == 4) {
                    bool valid = (lq * 4 + r) < 6;       // m < 70
                    aggv1 = fmaxf(aggv1, valid ? val : 0.f);
                } else if (mt <= 1) {
                    aggv0 = fmaxf(aggv0, val);
                } else if (mt == 3) {
                    aggv1 = fmaxf(aggv1, val);
                } else {                                  // mt==2 straddles t=35
                    if (m < TP) aggv0 = fmaxf(aggv0, val);
                    else        aggv1 = fmaxf(aggv1, val);
                }
                float mk = lmask[m];
                h2[m * 136 + u] = f2bf(val * mk);
            }
        }
        aggv0 = fmaxf(aggv0, __shfl_xor(aggv0, 16, 64));
        aggv0 = fmaxf(aggv0, __shfl_xor(aggv0, 32, 64));
        aggv1 = fmaxf(aggv1, __shfl_xor(aggv1, 16, 64));
        aggv1 = fmaxf(aggv1, __shfl_xor(aggv1, 32, 64));
        if (lq == 0) {
            agg2bf[u] = f2bf(aggv0);
            agg2bf[64 + u] = f2bf(aggv1);
        }
    }
    __syncthreads();
    // ---- fill h2 cols 64..127: agg2 * mask (pure selects) ----
    {
        int c = tid & 63;
        int r0 = tid >> 6;   // 0..3
        ushort a0 = agg2bf[c], a1v = agg2bf[64 + c];
#pragma unroll
        for (int j = 0; j < 20; ++j) {
            int row = r0 + j * 4;
            float mk = lmask[row];
            h2[row * 136 + 64 + c] = (mk != 0.f) ? ((row < TP) ? a0 : a1v) : (ushort)0;
        }
    }
    __syncthreads();
    // ---- phase C: pw3 = h2 @ Wd; bias folded out of max/min/sums ----
    {
        float mxa[2][2], mna[2][2], s1a[2], s2a[2];
#pragma unroll
        for (int s = 0; s < 2; ++s) {
            s1a[s] = 0.f; s2a[s] = 0.f;
#pragma unroll
            for (int v = 0; v < 2; ++v) { mxa[s][v] = -1e30f; mna[s][v] = 1e30f; }
        }
#pragma unroll
        for (int mt = 0; mt < 5; ++mt) {
            short8_t af[4];
#pragma unroll
            for (int kk = 0; kk < 4; ++kk)
                af[kk] = *(const short8_t*)(h2 + (mt * 16 + lr) * 136 + kk * 32 + lq * 8);
#pragma unroll
            for (int s = 0; s < 2; ++s) {
                f32x4 acc = {0.f, 0.f, 0.f, 0.f};
#pragma unroll
                for (int kk = 0; kk < 4; ++kk)
                    acc = __builtin_amdgcn_mfma_f32_16x16x32_bf16(af[kk], bfr[s][kk], acc, 0, 0, 0);
#pragma unroll
                for (int r = 0; r < 4; ++r) {
                    float a = acc[r];
                    s1a[s] += a;                       // pads: h2 row=0 -> a=0
                    s2a[s] = fmaf(a, a, s2a[s]);
                    if (mt == 4) {
                        bool valid = (lq * 4 + r) < 6;
                        mxa[s][1] = fmaxf(mxa[s][1], valid ? a : -1e30f);
                        mna[s][1] = fminf(mna[s][1], valid ? a : 1e30f);
                    } else if (mt <= 1) {
                        mxa[s][0] = fmaxf(mxa[s][0], a);
                        mna[s][0] = fminf(mna[s][0], a);
                    } else if (mt == 3) {
                        mxa[s][1] = fmaxf(mxa[s][1], a);
                        mna[s][1] = fminf(mna[s][1], a);
                    } else {
                        int m = 32 + lq * 4 + r;
                        int v = (m >= TP);
                        mxa[s][v] = fmaxf(mxa[s][v], a);
                        mna[s][v] = fminf(mna[s][v], a);
                    }
                }
            }
        }
#pragma unroll
        for (int s = 0; s < 2; ++s) {
#pragma unroll
            for (int v = 0; v < 2; ++v) {
                mxa[s][v] = fmaxf(mxa[s][v], __shfl_xor(mxa[s][v], 16, 64));
                mxa[s][v] = fmaxf(mxa[s][v], __shfl_xor(mxa[s][v], 32, 64));
                mna[s][v] = fminf(mna[s][v], __shfl_xor(mna[s][v], 16, 64));
                mna[s][v] = fminf(mna[s][v], __shfl_xor(mna[s][v], 32, 64));
            }
            s1a[s] += __shfl_xor(s1a[s], 16, 64); s1a[s] += __shfl_xor(s1a[s], 32, 64);
            s2a[s] += __shfl_xor(s2a[s], 16, 64); s2a[s] += __shfl_xor(s2a[s], 32, 64);
        }
        if (lq == 0) {
            int slot = blockIdx.x & 63;
#pragma unroll
            for (int s = 0; s < 2; ++s) {
                int u = u0 + s * 16 + lr;
                float bdu = bd[u];
                if (WSPATH) {
                    bool wantmin = (gd[u] < 0.f);   // sign(a3) == sign(gd)
#pragma unroll
                    for (int v = 0; v < 2; ++v) {
                        m3max[(size_t)(k0 + v) * 128 + u] = mxa[s][v] + bdu;
                        if (wantmin) m3min[(size_t)(k0 + v) * 128 + u] = mna[s][v] + bdu;
                    }
                } else {
#pragma unroll
                    for (int v = 0; v < 2; ++v)
                        outbuf[(size_t)u * KVOX + (k0 + v)] = mxa[s][v] + bdu;
                }
                atomicAdd(&slot3[slot * 256 + u], s1a[s]);
                atomicAdd(&slot3[slot * 256 + 128 + u], s2a[s]);
            }
        }
    }
}

// ---------------------------------------------------------------------------
// Finalize (ws path): out[u][k] = leaky(bn3(sel)) with LDS transpose.
// Address-select between max/min (min only valid where a3<0).
// ---------------------------------------------------------------------------
__global__ __launch_bounds__(256) void k_final_ws(const float* __restrict__ m3max,
                                                  const float* __restrict__ m3min,
                                                  const float* __restrict__ ws,
                                                  float* __restrict__ out) {
    __shared__ float tile[32][33];
    int tx = threadIdx.x & 31;
    int ty = threadIdx.x >> 5;
    int v0 = blockIdx.x * 32;
    int u0 = blockIdx.y * 32;
    const float* a3 = ws + PAR_A3;
    const float* c3 = ws + PAR_C3;
#pragma unroll
    for (int r = ty; r < 32; r += 8) {
        int v = v0 + r, u = u0 + tx;
        float y = 0.f;
        if (v < KVOX) {
            float a = a3[u], c = c3[u];
            const float* src = (a >= 0.f) ? m3max : m3min;
            float val = src[(size_t)v * 128 + u];
            y = a * val + c;
            y = (y >= 0.f) ? y : 0.1f * y;
        }
        tile[r][tx] = y;
    }
    __syncthreads();
#pragma unroll
    for (int r = ty; r < 32; r += 8) {
        int u = u0 + r, v = v0 + tx;
        if (v < KVOX) out[(size_t)u * KVOX + v] = tile[tx][r];
    }
}

__global__ __launch_bounds__(256) void k_final_inplace(const float* __restrict__ ws,
                                                       float* __restrict__ out) {
    int v = blockIdx.x * 256 + threadIdx.x;
    int u = blockIdx.y;
    if (v >= KVOX) return;
    float a = ws[PAR_A3 + u], c = ws[PAR_C3 + u];
    size_t idx = (size_t)u * KVOX + v;
    float y = a * out[idx] + c;
    out[idx] = (y >= 0.f) ? y : 0.1f * y;
}

// ---------------------------------------------------------------------------
extern "C" void kernel_launch(void* const* d_in, const int* in_sizes, int n_in,
                              void* d_out, int out_size, void* d_ws, size_t ws_size,
                              hipStream_t stream) {
    const float* x   = (const float*)d_in[0];
    const void*  coord = d_in[1];
    const float* W1  = (const float*)d_in[3];
    const float* b1  = (const float*)d_in[4];
    const float* g1  = (const float*)d_in[5];
    const float* be1 = (const float*)d_in[6];
    const float* W2  = (const float*)d_in[7];
    const float* b2  = (const float*)d_in[8];
    const float* g2  = (const float*)d_in[9];
    const float* be2 = (const float*)d_in[10];
    const float* Wd  = (const float*)d_in[11];
    const float* bd  = (const float*)d_in[12];
    const float* gd  = (const float*)d_in[13];
    const float* bed = (const float*)d_in[14];
    float* ws = (float*)d_ws;
    float* out = (float*)d_out;
    ushort* w2t = (ushort*)(ws + W2T_OFF);
    ushort* wdt = (ushort*)(ws + WDT_OFF);

    bool full = ws_size >= (size_t)WS_FULL_FLOATS * 4;
    const float invN = 1.f / (float)NPTS;

    hipMemsetAsync(d_ws, 0, (size_t)STATS_FLOATS * 4, stream);

    k_prep_stats1<<<64 + 1024, 256, 0, stream>>>(x, W1, b1, W2, Wd, w2t, wdt, ws + SLOT1_OFF);
    k_affine<<<1, 16, 0, stream>>>(ws + SLOT1_OFF, g1, be1, ws + PAR_A1, ws + PAR_C1, 16, invN);
    k_stats2<<<KVOX / 2, 256, 0, stream>>>(x, W1, b1, w2t, ws, ws + SLOT2_OFF);
    k_affine_b<<<1, 64, 0, stream>>>(ws + SLOT2_OFF, g2, be2, b2, ws + PAR_A2, ws + PAR_C2, 64, invN);
    if (full) {
        k_stage3<true><<<KVOX / 2, 256, 0, stream>>>(x, W1, b1, b2, w2t, wdt, bd, gd, ws,
                                                     ws + SLOT3_OFF, ws + M3MAX_OFF,
                                                     ws + M3MIN_OFF, out);
        k_affine_b<<<1, 128, 0, stream>>>(ws + SLOT3_OFF, gd, bed, bd, ws + PAR_A3, ws + PAR_C3, 128, invN);
        k_final_ws<<<dim3((KVOX + 31) / 32, 4), 256, 0, stream>>>(ws + M3MAX_OFF, ws + M3MIN_OFF, ws, out);
    } else {
        k_stage3<false><<<KVOX / 2, 256, 0, stream>>>(x, W1, b1, b2, w2t, wdt, bd, gd, ws,
                                                      ws + SLOT3_OFF, ws, ws, out);
        k_affine_b<<<1, 128, 0, stream>>>(ws + SLOT3_OFF, gd, bed, bd, ws + PAR_A3, ws + PAR_C3, 128, invN);
        k_final_inplace<<<dim3((KVOX + 255) / 256, 128), 256, 0, stream>>>(ws, out);
    }
    hipMemcpyAsync((char*)d_out + (size_t)128 * KVOX * 4, coord,
                   (size_t)KVOX * 4 * sizeof(int), hipMemcpyDeviceToDevice, stream);
}

// Round 4
// 180.561 us; speedup vs baseline: 6.9605x; 1.1580x over previous
//
#include <hip/hip_runtime.h>

#define KVOX 30000
#define TP 35
#define NPTS (KVOX * TP)
#define EPS_BN 1e-5f

typedef __attribute__((ext_vector_type(8))) short short8_t;   // 8 x bf16
typedef __attribute__((ext_vector_type(4))) float f32x4;

// ---- ws layout (float offsets) ----
#define SLOTG_OFF 0                  // 64 x 40 (35 used: G[28] | Sx[7])
#define SLOT2_OFF 2560               // 64 x 128
#define SLOT3_OFF 10752              // 64 x 256
#define PAR_A1 27136
#define PAR_C1 27152
#define PAR_A2 27168
#define PAR_C2 27232
#define PAR_A3 27296
#define PAR_C3 27424
#define STATS_FLOATS 27136           // memset region: slots only
#define W2T_OFF 27552                // 2048 bf16 = 1024 f
#define WDT_OFF 28576                // 16384 bf16 = 8192 f (sign-folded)
#define M3_OFF 36768                 // KVOX*128 f
#define SMALL_FLOATS (36768 + KVOX * 128)          // 3,876,768
#define H1G_OFF SMALL_FLOATS                        // KVOX*280 dwords (35 rows x 16 bf16)
#define AGG1G_OFF (H1G_OFF + KVOX * 280)            // KVOX*16 bf16 = KVOX*8 f
#define MASKG_OFF (AGG1G_OFF + KVOX * 8)            // KVOX*35 bf16
#define FULL_FLOATS (MASKG_OFF + (KVOX * 35 + 1) / 2)

__device__ __forceinline__ ushort f2bf(float f) {
    uint r;
    asm("v_cvt_pk_bf16_f32 %0, %1, %2" : "=v"(r) : "v"(f), "v"(f));
    return (ushort)r;
}
__device__ __forceinline__ uint f2bf2(float lo, float hi) {
    uint r;
    asm("v_cvt_pk_bf16_f32 %0, %1, %2" : "=v"(r) : "v"(lo), "v"(hi));
    return r;
}
__device__ __forceinline__ float bf2f(ushort h) {
    union { uint u; float f; } v; v.u = ((uint)h) << 16; return v.f;
}

// ---------------------------------------------------------------------------
// prep (blocks 0..63): W2T; WDT with sign(gd) folded. stats1 (64+): Gram sums.
// ---------------------------------------------------------------------------
__global__ __launch_bounds__(256) void k_prep_stats1(
    const float* __restrict__ x,
    const float* __restrict__ W2, const float* __restrict__ Wd,
    const float* __restrict__ gd,
    ushort* __restrict__ w2t, ushort* __restrict__ wdt,
    float* __restrict__ slotG) {
    if (blockIdx.x < 64) {
        int t = blockIdx.x * 256 + threadIdx.x;     // 0..16383
        if (t < 2048) {
            int u = t >> 5, k = t & 31;
            w2t[t] = f2bf(W2[k * 64 + u]);
        }
        int u = t >> 7, k = t & 127;
        float sg = (gd[u] < 0.f) ? -1.f : 1.f;
        wdt[t] = f2bf(Wd[k * 128 + u] * sg);
        return;
    }
    int bid = blockIdx.x - 64;                      // 0..255
    int tid = threadIdx.x;
    int gid = bid * 256 + tid;
    float sx[7], G[28];
#pragma unroll
    for (int c = 0; c < 7; ++c) sx[c] = 0.f;
#pragma unroll
    for (int i = 0; i < 28; ++i) G[i] = 0.f;
    for (int p = gid; p < NPTS; p += 256 * 256) {
        const float* xp = x + (size_t)p * 7;
        float xv[7];
#pragma unroll
        for (int c = 0; c < 7; ++c) { xv[c] = xp[c]; sx[c] += xv[c]; }
        int idx = 0;
#pragma unroll
        for (int i = 0; i < 7; ++i)
#pragma unroll
            for (int j = i; j < 7; ++j) { G[idx] = fmaf(xv[i], xv[j], G[idx]); ++idx; }
    }
    int lane = tid & 63;
    int wv = tid >> 6;
    int slot = (bid * 4 + wv) & 63;
#pragma unroll
    for (int k = 0; k < 35; ++k) {
        float v = (k < 28) ? G[k] : sx[k - 28];
#pragma unroll
        for (int m = 32; m > 0; m >>= 1) v += __shfl_xor(v, m, 64);
        if (lane == 0) atomicAdd(&slotG[slot * 40 + k], v);
    }
}

// BN1 finalize from Gram stats
__global__ void k_affine1g(const float* __restrict__ slotG,
                           const float* __restrict__ W1, const float* __restrict__ b1,
                           const float* __restrict__ g1, const float* __restrict__ be1,
                           float* __restrict__ pa, float* __restrict__ pc, float invN) {
    __shared__ float red[35];
    int t = threadIdx.x;     // 64 threads
    if (t < 35) {
        float s = 0.f;
#pragma unroll
        for (int sl = 0; sl < 64; ++sl) s += slotG[sl * 40 + t];
        red[t] = s;
    }
    __syncthreads();
    if (t < 16) {
        float wv[7];
#pragma unroll
        for (int c = 0; c < 7; ++c) wv[c] = W1[c * 16 + t];
        float b = b1[t];
        float sw = 0.f;
#pragma unroll
        for (int c = 0; c < 7; ++c) sw = fmaf(red[28 + c], wv[c], sw);
        float gq = 0.f;
        int idx = 0;
#pragma unroll
        for (int i = 0; i < 7; ++i)
#pragma unroll
            for (int j = i; j < 7; ++j) {
                float coef = wv[i] * wv[j];
                if (i != j) coef *= 2.f;
                gq = fmaf(coef, red[idx], gq);
                ++idx;
            }
        float mr = sw * invN;
        float mean = mr + b;
        float ex2 = gq * invN + 2.f * b * mr + b * b;
        float var = ex2 - mean * mean;
        float av = g1[t] * rsqrtf(var + EPS_BN);
        pa[t] = av;
        pc[t] = be1[t] - mean * av;
    }
}

// Bias-folded BN finalize: slots hold sums of (pw - b)
__global__ void k_affine_b(const float* __restrict__ slots,
                           const float* __restrict__ g,
                           const float* __restrict__ be,
                           const float* __restrict__ bias,
                           float* __restrict__ pa, float* __restrict__ pc,
                           int C, float invN) {
    int u = threadIdx.x;
    if (u >= C) return;
    float s = 0.f, q = 0.f;
    for (int sl = 0; sl < 64; ++sl) {
        s += slots[sl * 2 * C + u];
        q += slots[sl * 2 * C + C + u];
    }
    float b = bias[u];
    float mr = s * invN;
    float mean = mr + b;
    float ex2 = q * invN + 2.f * b * mr + b * b;
    float var = ex2 - mean * mean;
    float av = g[u] * rsqrtf(var + EPS_BN);
    pa[u] = av;
    pc[u] = be[u] - mean * av;
}

// Sign-aware variant for BN3: slots hold sums of sgn(g)*(pw - b)
__global__ void k_affine_b3(const float* __restrict__ slots,
                            const float* __restrict__ g,
                            const float* __restrict__ be,
                            const float* __restrict__ bias,
                            float* __restrict__ pa, float* __restrict__ pc,
                            int C, float invN) {
    int u = threadIdx.x;
    if (u >= C) return;
    float s = 0.f, q = 0.f;
    for (int sl = 0; sl < 64; ++sl) {
        s += slots[sl * 2 * C + u];
        q += slots[sl * 2 * C + C + u];
    }
    float sg = (g[u] < 0.f) ? -1.f : 1.f;
    s *= sg;
    float b = bias[u];
    float mr = s * invN;
    float mean = mr + b;
    float ex2 = q * invN + 2.f * b * mr + b * b;
    float var = ex2 - mean * mean;
    float av = g[u] * rsqrtf(var + EPS_BN);
    pa[u] = av;
    pc[u] = be[u] - mean * av;
}

// ---------------------------------------------------------------------------
// Phase A (256-thread): stage-1 VFE, 2 voxels -> h1 bf16 [80][40] masked.
// Outputs per-thread agg values g0o/g1o for uu = tid&15 (valid for tid<16).
// ---------------------------------------------------------------------------
__device__ __forceinline__ void phaseA(
    int k0, int tid,
    const float* __restrict__ x,
    const float* __restrict__ W1, const float* __restrict__ b1,
    const float* __restrict__ a1, const float* __restrict__ c1,
    ushort* __restrict__ h1, float* __restrict__ lmask, float* __restrict__ aggp,
    float& g0o, float& g1o) {
    int u = tid & 15;
    int g = tid >> 4;   // 0..15
    int v = g & 1;
    int th = g >> 1;    // 0..7
    float pmax = 0.f;
    if (th < 7) {
        float b1u = b1[u];
        float a1u = a1[u], c1u = c1[u];
        float w1c[7];
#pragma unroll
        for (int c = 0; c < 7; ++c) w1c[c] = W1[c * 16 + u];
#pragma unroll
        for (int i = 0; i < 5; ++i) {
            int t = th * 5 + i;
            const float* xp = x + ((size_t)(k0 + v) * TP + t) * 7;
            float xv[7];
            float sum7 = 0.f;
#pragma unroll
            for (int c = 0; c < 7; ++c) { xv[c] = xp[c]; sum7 += xv[c]; }
            float mk = (sum7 != 0.f) ? 1.f : 0.f;
            if (u == 0) lmask[v * TP + t] = mk;
            float val = b1u;
#pragma unroll
            for (int c = 0; c < 7; ++c) val = fmaf(xv[c], w1c[c], val);
            val = fmaxf(fmaf(a1u, val, c1u), 0.f);
            pmax = fmaxf(pmax, val);                 // unmasked (ref semantics)
            h1[(v * TP + t) * 40 + u] = f2bf(val * mk);
        }
    } else {
#pragma unroll
        for (int i = 0; i < 5; ++i) {
            int row = 70 + (g & 1) * 5 + i;
            h1[row * 40 + u] = 0;
            if (u == 0) lmask[row] = 0.f;
        }
    }
    pmax = fmaxf(pmax, __shfl_xor(pmax, 32, 64));
    int w = tid >> 6;
    int lane = tid & 63;
    if (lane < 32) aggp[w * 32 + lane] = pmax;       // lane = v*16+u
    __syncthreads();
    {
        int uu = tid & 15;
        int r0 = tid >> 4;  // 0..15
        float g0 = fmaxf(fmaxf(aggp[uu], aggp[32 + uu]),
                         fmaxf(aggp[64 + uu], aggp[96 + uu]));
        float g1 = fmaxf(fmaxf(aggp[16 + uu], aggp[48 + uu]),
                         fmaxf(aggp[80 + uu], aggp[112 + uu]));
        g0o = g0; g1o = g1;
        ushort a0 = f2bf(g0), a1b = f2bf(g1);
#pragma unroll
        for (int j = 0; j < 5; ++j) {
            int row = r0 + j * 16;
            float mk = lmask[row];
            h1[row * 40 + 16 + uu] = (mk != 0.f) ? ((row < TP) ? a0 : a1b) : (ushort)0;
        }
    }
    __syncthreads();
}

// ---------------------------------------------------------------------------
// S2: BN2 stats via MFMA; optionally dumps compact h1/agg1/mask to global.
// ---------------------------------------------------------------------------
template <bool DUMP>
__global__ __launch_bounds__(256, 8) void k_stats2(
    const float* __restrict__ x,
    const float* __restrict__ W1, const float* __restrict__ b1,
    const ushort* __restrict__ w2t,
    const float* __restrict__ ws,
    float* __restrict__ slot2,
    uint* __restrict__ h1G, ushort* __restrict__ agg1G, ushort* __restrict__ maskG) {
    __shared__ __align__(16) ushort h1[80 * 40];
    __shared__ float lmask[80];
    __shared__ float aggp[128];
    int tid = threadIdx.x;
    int k0 = blockIdx.x * 2;
    float g0, g1;
    phaseA(k0, tid, x, W1, b1, ws + PAR_A1, ws + PAR_C1, h1, lmask, aggp, g0, g1);
    if (DUMP) {
        for (int i = tid; i < 560; i += 256)
            h1G[(size_t)k0 * 280 + i] = ((const uint*)h1)[(i >> 3) * 20 + (i & 7)];
        if (tid < 16) {
            agg1G[k0 * 16 + tid] = f2bf(g0);
            agg1G[k0 * 16 + 16 + tid] = f2bf(g1);
        }
        if (tid < 70) maskG[k0 * 35 + tid] = f2bf(lmask[tid]);
    }
    int w = tid >> 6, lane = tid & 63, lq = lane >> 4, lr = lane & 15;
    int u = w * 16 + lr;
    short8_t bfrag = *(const short8_t*)(w2t + u * 32 + lq * 8);
    float s1v = 0.f, s2v = 0.f;
#pragma unroll
    for (int mt = 0; mt < 5; ++mt) {
        short8_t afrag = *(const short8_t*)(h1 + (mt * 16 + lr) * 40 + lq * 8);
        f32x4 acc = {0.f, 0.f, 0.f, 0.f};
        acc = __builtin_amdgcn_mfma_f32_16x16x32_bf16(afrag, bfrag, acc, 0, 0, 0);
#pragma unroll
        for (int r = 0; r < 4; ++r) { s1v += acc[r]; s2v = fmaf(acc[r], acc[r], s2v); }
    }
    s1v += __shfl_xor(s1v, 16, 64); s1v += __shfl_xor(s1v, 32, 64);
    s2v += __shfl_xor(s2v, 16, 64); s2v += __shfl_xor(s2v, 32, 64);
    if (lq == 0) {
        int slot = blockIdx.x & 63;
        atomicAdd(&slot2[slot * 128 + u], s1v);
        atomicAdd(&slot2[slot * 128 + 64 + u], s2v);
    }
}

// ---------------------------------------------------------------------------
// S3 REUSE path: 512 threads, stages h1 from global, sign-folded Wd.
// ---------------------------------------------------------------------------
__global__ __launch_bounds__(512, 8) void k_stage3_reuse(
    const uint* __restrict__ h1G, const ushort* __restrict__ agg1G,
    const ushort* __restrict__ maskG,
    const float* __restrict__ b2,
    const ushort* __restrict__ w2t, const ushort* __restrict__ wdt,
    const float* __restrict__ bd, const float* __restrict__ gd,
    const float* __restrict__ ws,
    float* __restrict__ slot3, float* __restrict__ m3) {
    __shared__ __align__(16) ushort h1[80 * 40];
    __shared__ __align__(16) ushort h2[80 * 136];
    __shared__ float lmask[80];
    __shared__ float aggh[2][2][64];   // [mhalf][vox][u]
    int tid = threadIdx.x;
    int k0 = blockIdx.x * 2;
    int w = tid >> 6, lane = tid & 63, lq = lane >> 4, lr = lane & 15;

    // ---- staging ----
    for (int i = tid; i < 560; i += 512)
        ((uint*)h1)[(i >> 3) * 20 + (i & 7)] = h1G[(size_t)k0 * 280 + i];
    if (tid < 200) ((uint*)h1)[1400 + tid] = 0u;   // rows 70..79 fully zero
    if (tid < 80) lmask[tid] = (tid < 70) ? bf2f(maskG[k0 * 35 + tid]) : 0.f;
    __syncthreads();
    {   // agg1 broadcast into cols 16..31
        int uu = tid & 15, r0 = tid >> 4;          // r0 0..31
        ushort a0 = agg1G[k0 * 16 + uu], a1 = agg1G[k0 * 16 + 16 + uu];
#pragma unroll
        for (int j = 0; j < 3; ++j) {
            int row = r0 + j * 32;
            if (row < 70) {
                float mk = lmask[row];
                h1[row * 40 + 16 + uu] = (mk != 0.f) ? ((row < TP) ? a0 : a1) : (ushort)0;
            }
        }
    }
    __syncthreads();
    // ---- phase B: waves split rows (mh=0: mt 0..2, mh=1: mt 3..4) ----
    {
        int uq = w & 3, mh = w >> 2;
        int u = uq * 16 + lr;
        short8_t bfrag = *(const short8_t*)(w2t + u * 32 + lq * 8);
        float a2u = (ws + PAR_A2)[u];
        float c2p = fmaf(a2u, b2[u], (ws + PAR_C2)[u]);
        float av0 = 0.f, av1 = 0.f;
#pragma unroll
        for (int mt = 0; mt < 5; ++mt) {
            if (mh == 0 ? (mt >= 3) : (mt < 3)) continue;
            short8_t afrag = *(const short8_t*)(h1 + (mt * 16 + lr) * 40 + lq * 8);
            f32x4 acc = {0.f, 0.f, 0.f, 0.f};
            acc = __builtin_amdgcn_mfma_f32_16x16x32_bf16(afrag, bfrag, acc, 0, 0, 0);
#pragma unroll
            for (int r = 0; r < 4; ++r) {
                int m = mt * 16 + lq * 4 + r;
                float val = fmaxf(fmaf(a2u, acc[r], c2p), 0.f);
                float vm = (m < 70) ? val : 0.f;
                if (m < TP) av0 = fmaxf(av0, vm); else av1 = fmaxf(av1, vm);
                h2[m * 136 + u] = f2bf(val * lmask[m]);
            }
        }
        av0 = fmaxf(av0, __shfl_xor(av0, 16, 64));
        av0 = fmaxf(av0, __shfl_xor(av0, 32, 64));
        av1 = fmaxf(av1, __shfl_xor(av1, 16, 64));
        av1 = fmaxf(av1, __shfl_xor(av1, 32, 64));
        if (lq == 0) { aggh[mh][0][u] = av0; aggh[mh][1][u] = av1; }
    }
    __syncthreads();
    // ---- h2 cols 64..127: packed b32 agg2*mask fill ----
    {
        int c2 = tid & 31;            // dword col
        int r0 = tid >> 5;            // 0..15
        float l0 = fmaxf(aggh[0][0][2 * c2], aggh[1][0][2 * c2]);
        float h0 = fmaxf(aggh[0][0][2 * c2 + 1], aggh[1][0][2 * c2 + 1]);
        float l1 = fmaxf(aggh[0][1][2 * c2], aggh[1][1][2 * c2]);
        float hh1 = fmaxf(aggh[0][1][2 * c2 + 1], aggh[1][1][2 * c2 + 1]);
        uint pk0 = f2bf2(l0, h0), pk1 = f2bf2(l1, hh1);
#pragma unroll
        for (int j = 0; j < 5; ++j) {
            int row = r0 + j * 16;
            float mk = lmask[row];
            uint val = (mk != 0.f) ? ((row < TP) ? pk0 : pk1) : 0u;
            *(uint*)(h2 + row * 136 + 64 + 2 * c2) = val;
        }
    }
    __syncthreads();
    // ---- phase C: wave w owns u-tile w; only max tracked (sign-folded) ----
    {
        int u = w * 16 + lr;
        short8_t bfr[4];
#pragma unroll
        for (int kk = 0; kk < 4; ++kk)
            bfr[kk] = *(const short8_t*)(wdt + (u * 128 + kk * 32 + lq * 8));
        float mx0 = -1e30f, mx1 = -1e30f, s1 = 0.f, s2 = 0.f;
#pragma unroll
        for (int mt = 0; mt < 5; ++mt) {
            short8_t af[4];
#pragma unroll
            for (int kk = 0; kk < 4; ++kk)
                af[kk] = *(const short8_t*)(h2 + (mt * 16 + lr) * 136 + kk * 32 + lq * 8);
            f32x4 acc = {0.f, 0.f, 0.f, 0.f};
#pragma unroll
            for (int kk = 0; kk < 4; ++kk)
                acc = __builtin_amdgcn_mfma_f32_16x16x32_bf16(af[kk], bfr[kk], acc, 0, 0, 0);
#pragma unroll
            for (int r = 0; r < 4; ++r) {
                float a = acc[r];
                s1 += a;
                s2 = fmaf(a, a, s2);
                int m = mt * 16 + lq * 4 + r;
                if (mt <= 1) mx0 = fmaxf(mx0, a);
                else if (mt == 3) mx1 = fmaxf(mx1, a);
                else if (mt == 2) { if (m < TP) mx0 = fmaxf(mx0, a); else mx1 = fmaxf(mx1, a); }
                else { if (m < 70) mx1 = fmaxf(mx1, a); }
            }
        }
        mx0 = fmaxf(mx0, __shfl_xor(mx0, 16, 64));
        mx0 = fmaxf(mx0, __shfl_xor(mx0, 32, 64));
        mx1 = fmaxf(mx1, __shfl_xor(mx1, 16, 64));
        mx1 = fmaxf(mx1, __shfl_xor(mx1, 32, 64));
        s1 += __shfl_xor(s1, 16, 64); s1 += __shfl_xor(s1, 32, 64);
        s2 += __shfl_xor(s2, 16, 64); s2 += __shfl_xor(s2, 32, 64);
        if (lq == 0) {
            float bdu = bd[u];
            float sg = (gd[u] < 0.f) ? -1.f : 1.f;
            m3[(size_t)k0 * 128 + u] = fmaf(sg, mx0, bdu);
            m3[(size_t)(k0 + 1) * 128 + u] = fmaf(sg, mx1, bdu);
            int slot = blockIdx.x & 63;
            atomicAdd(&slot3[slot * 256 + u], s1);
            atomicAdd(&slot3[slot * 256 + 128 + u], s2);
        }
    }
}

// ---------------------------------------------------------------------------
// S3 fallback (recomputes phase A, 256 threads), sign-folded.
// ---------------------------------------------------------------------------
template <bool WSPATH>
__global__ __launch_bounds__(256) void k_stage3_full(
    const float* __restrict__ x,
    const float* __restrict__ W1, const float* __restrict__ b1,
    const float* __restrict__ b2,
    const ushort* __restrict__ w2t, const ushort* __restrict__ wdt,
    const float* __restrict__ bd, const float* __restrict__ gd,
    const float* __restrict__ ws,
    float* __restrict__ slot3,
    float* __restrict__ m3, float* __restrict__ outbuf) {
    __shared__ __align__(16) ushort h1[80 * 40];
    __shared__ __align__(16) ushort h2[80 * 136];
    __shared__ float lmask[80];
    __shared__ float aggp[128];
    __shared__ ushort agg2bf[128];
    int tid = threadIdx.x;
    int k0 = blockIdx.x * 2;
    int w = tid >> 6, lane = tid & 63, lq = lane >> 4, lr = lane & 15;
    float gd0, gd1;
    phaseA(k0, tid, x, W1, b1, ws + PAR_A1, ws + PAR_C1, h1, lmask, aggp, gd0, gd1);

    int u0 = w * 32;
    short8_t bfr[2][4];
#pragma unroll
    for (int s = 0; s < 2; ++s)
#pragma unroll
        for (int kk = 0; kk < 4; ++kk)
            bfr[s][kk] = *(const short8_t*)(wdt + ((u0 + s * 16 + lr) * 128 + kk * 32 + lq * 8));

    {
        int u = w * 16 + lr;
        short8_t bfrag = *(const short8_t*)(w2t + u * 32 + lq * 8);
        float a2u = (ws + PAR_A2)[u];
        float c2p = fmaf(a2u, b2[u], (ws + PAR_C2)[u]);
        float aggv0 = 0.f, aggv1 = 0.f;
#pragma unroll
        for (int mt = 0; mt < 5; ++mt) {
            short8_t afrag = *(const short8_t*)(h1 + (mt * 16 + lr) * 40 + lq * 8);
            f32x4 acc = {0.f, 0.f, 0.f, 0.f};
            acc = __builtin_amdgcn_mfma_f32_16x16x32_bf16(afrag, bfrag, acc, 0, 0, 0);
#pragma unroll
            for (int r = 0; r < 4; ++r) {
                int m = mt * 16 + lq * 4 + r;
                float val = fmaxf(fmaf(a2u, acc[r], c2p), 0.f);
                float vm = (m < 70) ? val : 0.f;
                if (m < TP) aggv0 = fmaxf(aggv0, vm); else aggv1 = fmaxf(aggv1, vm);
                h2[m * 136 + u] = f2bf(val * lmask[m]);
            }
        }
        aggv0 = fmaxf(aggv0, __shfl_xor(aggv0, 16, 64));
        aggv0 = fmaxf(aggv0, __shfl_xor(aggv0, 32, 64));
        aggv1 = fmaxf(aggv1, __shfl_xor(aggv1, 16, 64));
        aggv1 = fmaxf(aggv1, __shfl_xor(aggv1, 32, 64));
        if (lq == 0) {
            agg2bf[u] = f2bf(aggv0);
            agg2bf[64 + u] = f2bf(aggv1);
        }
    }
    __syncthreads();
    {
        int c = tid & 63;
        int r0 = tid >> 6;
        ushort a0 = agg2bf[c], a1v = agg2bf[64 + c];
#pragma unroll
        for (int j = 0; j < 20; ++j) {
            int row = r0 + j * 4;
            float mk = lmask[row];
            h2[row * 136 + 64 + c] = (mk != 0.f) ? ((row < TP) ? a0 : a1v) : (ushort)0;
        }
    }
    __syncthreads();
    {
        float mxa[2][2], s1a[2], s2a[2];
#pragma unroll
        for (int s = 0; s < 2; ++s) {
            s1a[s] = 0.f; s2a[s] = 0.f;
            mxa[s][0] = -1e30f; mxa[s][1] = -1e30f;
        }
#pragma unroll
        for (int mt = 0; mt < 5; ++mt) {
            short8_t af[4];
#pragma unroll
            for (int kk = 0; kk < 4; ++kk)
                af[kk] = *(const short8_t*)(h2 + (mt * 16 + lr) * 136 + kk * 32 + lq * 8);
#pragma unroll
            for (int s = 0; s < 2; ++s) {
                f32x4 acc = {0.f, 0.f, 0.f, 0.f};
#pragma unroll
                for (int kk = 0; kk < 4; ++kk)
                    acc = __builtin_amdgcn_mfma_f32_16x16x32_bf16(af[kk], bfr[s][kk], acc, 0, 0, 0);
#pragma unroll
                for (int r = 0; r < 4; ++r) {
                    float a = acc[r];
                    s1a[s] += a;
                    s2a[s] = fmaf(a, a, s2a[s]);
                    int m = mt * 16 + lq * 4 + r;
                    if (mt <= 1) mxa[s][0] = fmaxf(mxa[s][0], a);
                    else if (mt == 3) mxa[s][1] = fmaxf(mxa[s][1], a);
                    else if (mt == 2) { if (m < TP) mxa[s][0] = fmaxf(mxa[s][0], a); else mxa[s][1] = fmaxf(mxa[s][1], a); }
                    else { if (m < 70) mxa[s][1] = fmaxf(mxa[s][1], a); }
                }
            }
        }
#pragma unroll
        for (int s = 0; s < 2; ++s) {
#pragma unroll
            for (int v = 0; v < 2; ++v) {
                mxa[s][v] = fmaxf(mxa[s][v], __shfl_xor(mxa[s][v], 16, 64));
                mxa[s][v] = fmaxf(mxa[s][v], __shfl_xor(mxa[s][v], 32, 64));
            }
            s1a[s] += __shfl_xor(s1a[s], 16, 64); s1a[s] += __shfl_xor(s1a[s], 32, 64);
            s2a[s] += __shfl_xor(s2a[s], 16, 64); s2a[s] += __shfl_xor(s2a[s], 32, 64);
        }
        if (lq == 0) {
            int slot = blockIdx.x & 63;
#pragma unroll
            for (int s = 0; s < 2; ++s) {
                int u = u0 + s * 16 + lr;
                float bdu = bd[u];
                float sg = (gd[u] < 0.f) ? -1.f : 1.f;
#pragma unroll
                for (int v = 0; v < 2; ++v) {
                    float res = fmaf(sg, mxa[s][v], bdu);
                    if (WSPATH) m3[(size_t)(k0 + v) * 128 + u] = res;
                    else        outbuf[(size_t)u * KVOX + (k0 + v)] = res;
                }
                atomicAdd(&slot3[slot * 256 + u], s1a[s]);
                atomicAdd(&slot3[slot * 256 + 128 + u], s2a[s]);
            }
        }
    }
}

// ---------------------------------------------------------------------------
// Finalize (ws path): out[u][k] = leaky(bn3(m3[k][u])) via LDS transpose
// ---------------------------------------------------------------------------
__global__ __launch_bounds__(256) void k_final_ws(const float* __restrict__ m3,
                                                  const float* __restrict__ ws,
                                                  float* __restrict__ out) {
    __shared__ float tile[32][33];
    int tx = threadIdx.x & 31;
    int ty = threadIdx.x >> 5;
    int v0 = blockIdx.x * 32;
    int u0 = blockIdx.y * 32;
    const float* a3 = ws + PAR_A3;
    const float* c3 = ws + PAR_C3;
#pragma unroll
    for (int r = ty; r < 32; r += 8) {
        int v = v0 + r, u = u0 + tx;
        float y = 0.f;
        if (v < KVOX) {
            float a = a3[u], c = c3[u];
            float val = m3[(size_t)v * 128 + u];
            y = a * val + c;
            y = (y >= 0.f) ? y : 0.1f * y;
        }
        tile[r][tx] = y;
    }
    __syncthreads();
#pragma unroll
    for (int r = ty; r < 32; r += 8) {
        int u = u0 + r, v = v0 + tx;
        if (v < KVOX) out[(size_t)u * KVOX + v] = tile[tx][r];
    }
}

__global__ __launch_bounds__(256) void k_final_inplace(const float* __restrict__ ws,
                                                       float* __restrict__ out) {
    int v = blockIdx.x * 256 + threadIdx.x;
    int u = blockIdx.y;
    if (v >= KVOX) return;
    float a = ws[PAR_A3 + u], c = ws[PAR_C3 + u];
    size_t idx = (size_t)u * KVOX + v;
    float y = a * out[idx] + c;
    out[idx] = (y >= 0.f) ? y : 0.1f * y;
}

// ---------------------------------------------------------------------------
extern "C" void kernel_launch(void* const* d_in, const int* in_sizes, int n_in,
                              void* d_out, int out_size, void* d_ws, size_t ws_size,
                              hipStream_t stream) {
    const float* x   = (const float*)d_in[0];
    const void*  coord = d_in[1];
    const float* W1  = (const float*)d_in[3];
    const float* b1  = (const float*)d_in[4];
    const float* g1  = (const float*)d_in[5];
    const float* be1 = (const float*)d_in[6];
    const float* W2  = (const float*)d_in[7];
    const float* b2  = (const float*)d_in[8];
    const float* g2  = (const float*)d_in[9];
    const float* be2 = (const float*)d_in[10];
    const float* Wd  = (const float*)d_in[11];
    const float* bd  = (const float*)d_in[12];
    const float* gd  = (const float*)d_in[13];
    const float* bed = (const float*)d_in[14];
    float* ws = (float*)d_ws;
    float* out = (float*)d_out;
    ushort* w2t = (ushort*)(ws + W2T_OFF);
    ushort* wdt = (ushort*)(ws + WDT_OFF);
    uint* h1G = (uint*)(ws + H1G_OFF);
    ushort* agg1G = (ushort*)(ws + AGG1G_OFF);
    ushort* maskG = (ushort*)(ws + MASKG_OFF);

    size_t wsf = ws_size / 4;
    bool full = wsf >= (size_t)FULL_FLOATS;
    bool small = wsf >= (size_t)SMALL_FLOATS;
    const float invN = 1.f / (float)NPTS;

    hipMemsetAsync(d_ws, 0, (size_t)STATS_FLOATS * 4, stream);

    k_prep_stats1<<<64 + 256, 256, 0, stream>>>(x, W2, Wd, gd, w2t, wdt, ws + SLOTG_OFF);
    k_affine1g<<<1, 64, 0, stream>>>(ws + SLOTG_OFF, W1, b1, g1, be1, ws + PAR_A1, ws + PAR_C1, invN);
    if (full)
        k_stats2<true><<<KVOX / 2, 256, 0, stream>>>(x, W1, b1, w2t, ws, ws + SLOT2_OFF, h1G, agg1G, maskG);
    else
        k_stats2<false><<<KVOX / 2, 256, 0, stream>>>(x, W1, b1, w2t, ws, ws + SLOT2_OFF, h1G, agg1G, maskG);
    k_affine_b<<<1, 64, 0, stream>>>(ws + SLOT2_OFF, g2, be2, b2, ws + PAR_A2, ws + PAR_C2, 64, invN);

    if (full) {
        k_stage3_reuse<<<KVOX / 2, 512, 0, stream>>>(h1G, agg1G, maskG, b2, w2t, wdt, bd, gd, ws,
                                                     ws + SLOT3_OFF, ws + M3_OFF);
        k_affine_b3<<<1, 128, 0, stream>>>(ws + SLOT3_OFF, gd, bed, bd, ws + PAR_A3, ws + PAR_C3, 128, invN);
        k_final_ws<<<dim3((KVOX + 31) / 32, 4), 256, 0, stream>>>(ws + M3_OFF, ws, out);
    } else if (small) {
        k_stage3_full<true><<<KVOX / 2, 256, 0, stream>>>(x, W1, b1, b2, w2t, wdt, bd, gd, ws,
                                                          ws + SLOT3_OFF, ws + M3_OFF, out);
        k_affine_b3<<<1, 128, 0, stream>>>(ws + SLOT3_OFF, gd, bed, bd, ws + PAR_A3, ws + PAR_C3, 128, invN);
        k_final_ws<<<dim3((KVOX + 31) / 32, 4), 256, 0, stream>>>(ws + M3_OFF, ws, out);
    } else {
        k_stage3_full<false><<<KVOX / 2, 256, 0, stream>>>(x, W1, b1, b2, w2t, wdt, bd, gd, ws,
                                                           ws + SLOT3_OFF, ws, out);
        k_affine_b3<<<1, 128, 0, stream>>>(ws + SLOT3_OFF, gd, bed, bd, ws + PAR_A3, ws + PAR_C3, 128, invN);
        k_final_inplace<<<dim3((KVOX + 255) / 256, 128), 256, 0, stream>>>(ws, out);
    }
    hipMemcpyAsync((char*)d_out + (size_t)128 * KVOX * 4, coord,
                   (size_t)KVOX * 4 * sizeof(int), hipMemcpyDeviceToDevice, stream);
}

// Round 5
// 176.289 us; speedup vs baseline: 7.1292x; 1.0242x over previous
//
#include <hip/hip_runtime.h>

#define KVOX 30000
#define TP 35
#define NPTS (KVOX * TP)
#define EPS_BN 1e-5f

typedef __attribute__((ext_vector_type(8))) short short8_t;   // 8 x bf16
typedef __attribute__((ext_vector_type(4))) float f32x4;
typedef __attribute__((ext_vector_type(2))) float f32x2;

#define MFMA_BF16 __builtin_amdgcn_mfma_f32_16x16x32_bf16

// ---- ws layout (float offsets) ----
#define SLOTG_OFF 0                  // 64 x 40 (35 used: G[28] | Sx[7])
#define SLOT2_OFF 2560               // 64 x 128
#define SLOT3_OFF 10752              // 64 x 256
#define PAR_A1 27136
#define PAR_C1 27152
#define PAR_A2 27168
#define PAR_C2 27232
#define PAR_A3 27296
#define PAR_C3 27424
#define STATS_FLOATS 27136           // memset region: slots only
#define W2T_OFF 27552                // [64 u][32 k] bf16
#define WDT_OFF 28576                // [128 u][128 k] bf16 (sign-folded)
#define M3_OFF 36768                 // KVOX*128 bf16 = KVOX*64 floats
#define SMALL_FLOATS (36768 + KVOX * 64)
#define H1G_OFF SMALL_FLOATS         // dword records per block
#define REC_DW 696                   // 640 h1 (80 rows x 16 bf16) + 16 agg1 + 40 mask
#define FULL_FLOATS (H1G_OFF + (KVOX / 2) * REC_DW)

__device__ __forceinline__ ushort f2bf(float f) {
    uint r;
    asm("v_cvt_pk_bf16_f32 %0, %1, %2" : "=v"(r) : "v"(f), "v"(f));
    return (ushort)r;
}
__device__ __forceinline__ uint f2bf2(float lo, float hi) {
    uint r;
    asm("v_cvt_pk_bf16_f32 %0, %1, %2" : "=v"(r) : "v"(lo), "v"(hi));
    return r;
}
__device__ __forceinline__ float bf2f(ushort h) {
    union { uint u; float f; } v; v.u = ((uint)h) << 16; return v.f;
}
__device__ __forceinline__ f32x2 mk2(float a, float b) {
    f32x2 r; r[0] = a; r[1] = b; return r;
}

// ---------------------------------------------------------------------------
// prep (blocks 0..63): W2T; WDT with sign(gd) folded. stats1 (64+): Gram sums.
// ---------------------------------------------------------------------------
__global__ __launch_bounds__(256) void k_prep_stats1(
    const float* __restrict__ x,
    const float* __restrict__ W2, const float* __restrict__ Wd,
    const float* __restrict__ gd,
    ushort* __restrict__ w2t, ushort* __restrict__ wdt,
    float* __restrict__ slotG) {
    if (blockIdx.x < 64) {
        int t = blockIdx.x * 256 + threadIdx.x;     // 0..16383
        if (t < 2048) {
            int u = t >> 5, k = t & 31;
            w2t[t] = f2bf(W2[k * 64 + u]);
        }
        int u = t >> 7, k = t & 127;
        float sg = (gd[u] < 0.f) ? -1.f : 1.f;
        wdt[t] = f2bf(Wd[k * 128 + u] * sg);
        return;
    }
    int bid = blockIdx.x - 64;                      // 0..255
    int tid = threadIdx.x;
    int gid = bid * 256 + tid;
    float sx[7], G[28];
#pragma unroll
    for (int c = 0; c < 7; ++c) sx[c] = 0.f;
#pragma unroll
    for (int i = 0; i < 28; ++i) G[i] = 0.f;
    for (int p = gid; p < NPTS; p += 256 * 256) {
        const float* xp = x + (size_t)p * 7;
        float xv[7];
#pragma unroll
        for (int c = 0; c < 7; ++c) { xv[c] = xp[c]; sx[c] += xv[c]; }
        int idx = 0;
#pragma unroll
        for (int i = 0; i < 7; ++i)
#pragma unroll
            for (int j = i; j < 7; ++j) { G[idx] = fmaf(xv[i], xv[j], G[idx]); ++idx; }
    }
    int lane = tid & 63;
    int wv = tid >> 6;
    int slot = (bid * 4 + wv) & 63;
#pragma unroll
    for (int k = 0; k < 35; ++k) {
        float v = (k < 28) ? G[k] : sx[k - 28];
#pragma unroll
        for (int m = 32; m > 0; m >>= 1) v += __shfl_xor(v, m, 64);
        if (lane == 0) atomicAdd(&slotG[slot * 40 + k], v);
    }
}

// BN1 finalize from Gram stats
__global__ void k_affine1g(const float* __restrict__ slotG,
                           const float* __restrict__ W1, const float* __restrict__ b1,
                           const float* __restrict__ g1, const float* __restrict__ be1,
                           float* __restrict__ pa, float* __restrict__ pc, float invN) {
    __shared__ float red[35];
    int t = threadIdx.x;     // 64 threads
    if (t < 35) {
        float s = 0.f;
#pragma unroll
        for (int sl = 0; sl < 64; ++sl) s += slotG[sl * 40 + t];
        red[t] = s;
    }
    __syncthreads();
    if (t < 16) {
        float wv[7];
#pragma unroll
        for (int c = 0; c < 7; ++c) wv[c] = W1[c * 16 + t];
        float b = b1[t];
        float sw = 0.f;
#pragma unroll
        for (int c = 0; c < 7; ++c) sw = fmaf(red[28 + c], wv[c], sw);
        float gq = 0.f;
        int idx = 0;
#pragma unroll
        for (int i = 0; i < 7; ++i)
#pragma unroll
            for (int j = i; j < 7; ++j) {
                float coef = wv[i] * wv[j];
                if (i != j) coef *= 2.f;
                gq = fmaf(coef, red[idx], gq);
                ++idx;
            }
        float mr = sw * invN;
        float mean = mr + b;
        float ex2 = gq * invN + 2.f * b * mr + b * b;
        float var = ex2 - mean * mean;
        float av = g1[t] * rsqrtf(var + EPS_BN);
        pa[t] = av;
        pc[t] = be1[t] - mean * av;
    }
}

// Bias-folded BN finalize: slots hold sums of (pw - b)
__global__ void k_affine_b(const float* __restrict__ slots,
                           const float* __restrict__ g,
                           const float* __restrict__ be,
                           const float* __restrict__ bias,
                           float* __restrict__ pa, float* __restrict__ pc,
                           int C, float invN) {
    int u = threadIdx.x;
    if (u >= C) return;
    float s = 0.f, q = 0.f;
    for (int sl = 0; sl < 64; ++sl) {
        s += slots[sl * 2 * C + u];
        q += slots[sl * 2 * C + C + u];
    }
    float b = bias[u];
    float mr = s * invN;
    float mean = mr + b;
    float ex2 = q * invN + 2.f * b * mr + b * b;
    float var = ex2 - mean * mean;
    float av = g[u] * rsqrtf(var + EPS_BN);
    pa[u] = av;
    pc[u] = be[u] - mean * av;
}

// Sign-aware variant for BN3: slots hold sums of sgn(g)*(pw - b)
__global__ void k_affine_b3(const float* __restrict__ slots,
                            const float* __restrict__ g,
                            const float* __restrict__ be,
                            const float* __restrict__ bias,
                            float* __restrict__ pa, float* __restrict__ pc,
                            int C, float invN) {
    int u = threadIdx.x;
    if (u >= C) return;
    float s = 0.f, q = 0.f;
    for (int sl = 0; sl < 64; ++sl) {
        s += slots[sl * 2 * C + u];
        q += slots[sl * 2 * C + C + u];
    }
    float sg = (g[u] < 0.f) ? -1.f : 1.f;
    s *= sg;
    float b = bias[u];
    float mr = s * invN;
    float mean = mr + b;
    float ex2 = q * invN + 2.f * b * mr + b * b;
    float var = ex2 - mean * mean;
    float av = g[u] * rsqrtf(var + EPS_BN);
    pa[u] = av;
    pc[u] = be[u] - mean * av;
}

// ---------------------------------------------------------------------------
// Phase A (interleaved rows, 256 thr): h1 bf16 [80][24] masked, row = 2t+v.
// agg1 (unmasked max) -> agg1bf [2][16] bf16 LDS. lmask[80] f32 (pads 0).
// ---------------------------------------------------------------------------
__device__ __forceinline__ void phaseA_il(
    int k0, int tid,
    const float* __restrict__ x,
    const float* __restrict__ W1, const float* __restrict__ b1,
    const float* __restrict__ a1, const float* __restrict__ c1,
    ushort* __restrict__ h1, float* __restrict__ lmask,
    float* __restrict__ aggp, ushort* __restrict__ agg1bf) {
    int u = tid & 15;
    int g = tid >> 4;   // 0..15
    int v = g & 1;
    int th = g >> 1;    // 0..7
    float pmax = 0.f;
    if (th < 7) {
        float b1u = b1[u];
        float a1u = a1[u], c1u = c1[u];
        float w1c[7];
#pragma unroll
        for (int c = 0; c < 7; ++c) w1c[c] = W1[c * 16 + u];
#pragma unroll
        for (int i = 0; i < 5; ++i) {
            int t = th * 5 + i;
            const float* xp = x + ((size_t)(k0 + v) * TP + t) * 7;
            float xv[7];
            float sum7 = 0.f;
#pragma unroll
            for (int c = 0; c < 7; ++c) { xv[c] = xp[c]; sum7 += xv[c]; }
            float mkv = (sum7 != 0.f) ? 1.f : 0.f;
            int row = 2 * t + v;
            if (u == 0) lmask[row] = mkv;
            float val = b1u;
#pragma unroll
            for (int c = 0; c < 7; ++c) val = fmaf(xv[c], w1c[c], val);
            val = fmaxf(fmaf(a1u, val, c1u), 0.f);
            pmax = fmaxf(pmax, val);                 // unmasked (ref semantics)
            h1[row * 24 + u] = f2bf(val * mkv);
        }
    } else if (g < 16) {
        // zero pad rows 70..79 (cols 0..15) + pad lmask
#pragma unroll
        for (int i = 0; i < 5; ++i) {
            int row = 70 + (g & 1) + 2 * i;
            h1[row * 24 + u] = 0;
            if (u == 0) lmask[row] = 0.f;
        }
    }
    pmax = fmaxf(pmax, __shfl_xor(pmax, 32, 64));
    int w = tid >> 6;
    int lane = tid & 63;
    if (lane < 32 && w < 4) aggp[w * 32 + lane] = pmax;   // lane = v*16+u
    __syncthreads();
    if (tid < 16) {
        float g0 = fmaxf(fmaxf(aggp[u], aggp[32 + u]),
                         fmaxf(aggp[64 + u], aggp[96 + u]));
        float g1 = fmaxf(fmaxf(aggp[16 + u], aggp[48 + u]),
                         fmaxf(aggp[80 + u], aggp[112 + u]));
        agg1bf[u] = f2bf(g0);
        agg1bf[16 + u] = f2bf(g1);
    }
    __syncthreads();
}

// ---------------------------------------------------------------------------
// S2: BN2 stats via rank-1 MFMA; optionally dumps h1/agg1/mask record.
// ---------------------------------------------------------------------------
template <bool DUMP>
__global__ __launch_bounds__(256, 8) void k_stats2(
    const float* __restrict__ x,
    const float* __restrict__ W1, const float* __restrict__ b1,
    const ushort* __restrict__ w2t,
    const float* __restrict__ ws,
    float* __restrict__ slot2, uint* __restrict__ recs) {
    __shared__ __align__(16) ushort h1[80 * 24];
    __shared__ float lmask[80];
    __shared__ float aggp[128];
    __shared__ __align__(16) ushort agg1bf[32];
    __shared__ __align__(16) uint zeros16[4];
    int tid = threadIdx.x;
    int k0 = blockIdx.x * 2;
    if (tid < 4) zeros16[tid] = 0;
    phaseA_il(k0, tid, x, W1, b1, ws + PAR_A1, ws + PAR_C1, h1, lmask, aggp, agg1bf);
    if (DUMP) {
        uint* rec = recs + (size_t)blockIdx.x * REC_DW;
        const uint* h1dw = (const uint*)h1;
        for (int i = tid; i < 640; i += 256) rec[i] = h1dw[(i >> 3) * 12 + (i & 7)];
        if (tid < 16) rec[640 + tid] = ((const uint*)agg1bf)[tid];
        if (tid < 40) rec[656 + tid] = f2bf2(lmask[2 * tid], lmask[2 * tid + 1]);
    }
    int w = tid >> 6, lane = tid & 63, lq = lane >> 4, lr = lane & 15;
    int u = w * 16 + lr;
    short8_t bB = *(const short8_t*)(w2t + u * 32 + (lq & 1) * 8);
    // proj1 = agg1 @ W2[16:32]
    const ushort* pa = (lq < 2) ? (agg1bf + (lr & 1) * 16 + lq * 8) : (const ushort*)zeros16;
    short8_t pAf = *(const short8_t*)pa;
    short8_t bP = *(const short8_t*)(w2t + u * 32 + 16 + (lq & 1) * 8);
    f32x4 aP = {0.f, 0.f, 0.f, 0.f};
    aP = MFMA_BF16(pAf, bP, aP, 0, 0, 0);
    f32x2 p1p = mk2(__shfl(aP[0], lr, 64), __shfl(aP[1], lr, 64));
    f32x2 s1p = {0.f, 0.f}, s2p = {0.f, 0.f};
#pragma unroll
    for (int mt = 0; mt < 5; ++mt) {
        const ushort* ha = (lq < 2) ? (h1 + (mt * 16 + lr) * 24 + lq * 8) : (const ushort*)zeros16;
        short8_t af = *(const short8_t*)ha;
        f32x4 acc = {0.f, 0.f, 0.f, 0.f};
        acc = MFMA_BF16(af, bB, acc, 0, 0, 0);
        const f32x4 mk = *(const f32x4*)(lmask + mt * 16 + lq * 4);
        f32x2 am01 = (mk2(acc[0], acc[1]) + p1p) * mk2(mk[0], mk[1]);
        f32x2 am23 = (mk2(acc[2], acc[3]) + p1p) * mk2(mk[2], mk[3]);
        s1p += am01 + am23;
        s2p += am01 * am01;
        s2p += am23 * am23;
    }
    float s1 = s1p[0] + s1p[1], s2 = s2p[0] + s2p[1];
    s1 += __shfl_xor(s1, 16, 64); s1 += __shfl_xor(s1, 32, 64);
    s2 += __shfl_xor(s2, 16, 64); s2 += __shfl_xor(s2, 32, 64);
    if (lq == 0) {
        int slot = blockIdx.x & 63;
        atomicAdd(&slot2[slot * 128 + u], s1);
        atomicAdd(&slot2[slot * 128 + 64 + u], s2);
    }
}

// ---------------------------------------------------------------------------
// S3 REUSE: 512 thr; stages h1 record; rank-1 agg on both layers; pk epilogues
// ---------------------------------------------------------------------------
__global__ __launch_bounds__(512, 8) void k_stage3_reuse(
    const uint* __restrict__ recs,
    const float* __restrict__ b2,
    const ushort* __restrict__ w2t, const ushort* __restrict__ wdt,
    const float* __restrict__ bd, const float* __restrict__ gd,
    const float* __restrict__ ws,
    float* __restrict__ slot3, ushort* __restrict__ m3) {
    __shared__ __align__(16) ushort h1[80 * 24];
    __shared__ __align__(16) ushort h2[80 * 72];
    __shared__ float lmask[80];
    __shared__ float aggh[2][2][64];                 // [mhalf][vox][u]
    __shared__ __align__(16) ushort agg1bf[32];
    __shared__ __align__(16) ushort agg2bf[2 * 64];  // [vox][64] bf16
    __shared__ __align__(16) uint zeros16[4];
    int tid = threadIdx.x;
    int k0 = blockIdx.x * 2;
    int w = tid >> 6, lane = tid & 63, lq = lane >> 4, lr = lane & 15;

    // ---- staging ----
    {
        const uint* rec = recs + (size_t)blockIdx.x * REC_DW;
        uint* h1dw = (uint*)h1;
        h1dw[(tid >> 3) * 12 + (tid & 7)] = rec[tid];          // 0..511
        if (tid < 184) {
            int i2 = 512 + tid;
            if (i2 < 640) h1dw[(i2 >> 3) * 12 + (i2 & 7)] = rec[i2];
            else if (i2 < 656) ((uint*)agg1bf)[i2 - 640] = rec[i2];
            else {
                uint mw = rec[i2];
                int j = i2 - 656;
                lmask[2 * j] = bf2f((ushort)(mw & 0xffffu));
                lmask[2 * j + 1] = bf2f((ushort)(mw >> 16));
            }
        }
        if (tid < 4) zeros16[tid] = 0;
    }
    __syncthreads();

    // ---- phase B: pw2n via rank-1; h2 [80][64+pad8] UNMASKED ----
    {
        int mh = w >> 2, uq = w & 3;
        int u = uq * 16 + lr;
        short8_t bB = *(const short8_t*)(w2t + u * 32 + (lq & 1) * 8);
        const ushort* pa = (lq < 2) ? (agg1bf + (lr & 1) * 16 + lq * 8) : (const ushort*)zeros16;
        short8_t pAf = *(const short8_t*)pa;
        short8_t bP = *(const short8_t*)(w2t + u * 32 + 16 + (lq & 1) * 8);
        f32x4 aP = {0.f, 0.f, 0.f, 0.f};
        aP = MFMA_BF16(pAf, bP, aP, 0, 0, 0);
        f32x2 p1p = mk2(__shfl(aP[0], lr, 64), __shfl(aP[1], lr, 64));
        float a2u = ws[PAR_A2 + u];
        float c2u = fmaf(a2u, b2[u], ws[PAR_C2 + u]);
        f32x2 a2p = mk2(a2u, a2u), c2p = mk2(c2u, c2u);
        float av0 = 0.f, av1 = 0.f;
        int mt0 = mh ? 3 : 0, mt1 = mh ? 5 : 3;
        for (int mt = mt0; mt < mt1; ++mt) {
            const ushort* ha = (lq < 2) ? (h1 + (mt * 16 + lr) * 24 + lq * 8) : (const ushort*)zeros16;
            short8_t af = *(const short8_t*)ha;
            f32x4 acc = {0.f, 0.f, 0.f, 0.f};
            acc = MFMA_BF16(af, bB, acc, 0, 0, 0);
            const f32x4 mk = *(const f32x4*)(lmask + mt * 16 + lq * 4);
            int m0 = mt * 16 + lq * 4;
            f32x2 am01 = (mk2(acc[0], acc[1]) + p1p) * mk2(mk[0], mk[1]);
            f32x2 am23 = (mk2(acc[2], acc[3]) + p1p) * mk2(mk[2], mk[3]);
            f32x2 t01 = a2p * am01 + c2p;
            f32x2 t23 = a2p * am23 + c2p;
            float v0 = fmaxf(t01[0], 0.f), v1 = fmaxf(t01[1], 0.f);
            float v2 = fmaxf(t23[0], 0.f), v3 = fmaxf(t23[1], 0.f);
            h2[(m0 + 0) * 72 + u] = f2bf(v0);
            h2[(m0 + 1) * 72 + u] = f2bf(v1);
            h2[(m0 + 2) * 72 + u] = f2bf(v2);
            h2[(m0 + 3) * 72 + u] = f2bf(v3);
            if (mt == 4) {                           // exclude pad rows from agg
                bool c01 = lq < 2, c23 = lq < 1;
                v0 = c01 ? v0 : 0.f; v1 = c01 ? v1 : 0.f;
                v2 = c23 ? v2 : 0.f; v3 = c23 ? v3 : 0.f;
            }
            av0 = fmaxf(av0, fmaxf(v0, v2));
            av1 = fmaxf(av1, fmaxf(v1, v3));
        }
        av0 = fmaxf(av0, __shfl_xor(av0, 16, 64));
        av0 = fmaxf(av0, __shfl_xor(av0, 32, 64));
        av1 = fmaxf(av1, __shfl_xor(av1, 16, 64));
        av1 = fmaxf(av1, __shfl_xor(av1, 32, 64));
        if (lq == 0) { aggh[mh][0][u] = av0; aggh[mh][1][u] = av1; }
    }
    __syncthreads();
    if (tid < 32) {                                   // pack agg2 -> bf16 [2][64]
        int u2 = tid;
        float l0 = fmaxf(aggh[0][0][2 * u2], aggh[1][0][2 * u2]);
        float h0 = fmaxf(aggh[0][0][2 * u2 + 1], aggh[1][0][2 * u2 + 1]);
        float l1 = fmaxf(aggh[0][1][2 * u2], aggh[1][1][2 * u2]);
        float h1v = fmaxf(aggh[0][1][2 * u2 + 1], aggh[1][1][2 * u2 + 1]);
        ((uint*)agg2bf)[u2] = f2bf2(l0, h0);
        ((uint*)agg2bf)[32 + u2] = f2bf2(l1, h1v);
    }
    __syncthreads();

    // ---- phase C: pw3 = h2a@Wd[0:64] + mask*proj2; max/sum/sumsq ----
    {
        int u = w * 16 + lr;
        short8_t bM0 = *(const short8_t*)(wdt + u * 128 + lq * 8);
        short8_t bM1 = *(const short8_t*)(wdt + u * 128 + 32 + lq * 8);
        short8_t bP0 = *(const short8_t*)(wdt + u * 128 + 64 + lq * 8);
        short8_t bP1 = *(const short8_t*)(wdt + u * 128 + 96 + lq * 8);
        short8_t pA0 = *(const short8_t*)(agg2bf + (lr & 1) * 64 + lq * 8);
        short8_t pA1 = *(const short8_t*)(agg2bf + (lr & 1) * 64 + 32 + lq * 8);
        f32x4 aP = {0.f, 0.f, 0.f, 0.f};
        aP = MFMA_BF16(pA0, bP0, aP, 0, 0, 0);
        aP = MFMA_BF16(pA1, bP1, aP, 0, 0, 0);
        f32x2 p2p = mk2(__shfl(aP[0], lr, 64), __shfl(aP[1], lr, 64));
        float mx0 = -1e30f, mx1 = -1e30f;
        f32x2 s1p = {0.f, 0.f}, s2p = {0.f, 0.f};
#pragma unroll
        for (int mt = 0; mt < 5; ++mt) {
            const ushort* hrow = h2 + (mt * 16 + lr) * 72;
            short8_t a0 = *(const short8_t*)(hrow + lq * 8);
            short8_t a1 = *(const short8_t*)(hrow + 32 + lq * 8);
            f32x4 acc = {0.f, 0.f, 0.f, 0.f};
            acc = MFMA_BF16(a0, bM0, acc, 0, 0, 0);
            acc = MFMA_BF16(a1, bM1, acc, 0, 0, 0);
            const f32x4 mk = *(const f32x4*)(lmask + mt * 16 + lq * 4);
            f32x2 am01 = (mk2(acc[0], acc[1]) + p2p) * mk2(mk[0], mk[1]);
            f32x2 am23 = (mk2(acc[2], acc[3]) + p2p) * mk2(mk[2], mk[3]);
            s1p += am01 + am23;
            s2p += am01 * am01;
            s2p += am23 * am23;
            if (mt < 4) {
                mx0 = fmaxf(mx0, fmaxf(am01[0], am23[0]));
                mx1 = fmaxf(mx1, fmaxf(am01[1], am23[1]));
            } else {
                bool c01 = lq < 2, c23 = lq < 1;
                mx0 = fmaxf(mx0, fmaxf(c01 ? am01[0] : -1e30f, c23 ? am23[0] : -1e30f));
                mx1 = fmaxf(mx1, fmaxf(c01 ? am01[1] : -1e30f, c23 ? am23[1] : -1e30f));
            }
        }
        mx0 = fmaxf(mx0, __shfl_xor(mx0, 16, 64));
        mx0 = fmaxf(mx0, __shfl_xor(mx0, 32, 64));
        mx1 = fmaxf(mx1, __shfl_xor(mx1, 16, 64));
        mx1 = fmaxf(mx1, __shfl_xor(mx1, 32, 64));
        float s1 = s1p[0] + s1p[1], s2 = s2p[0] + s2p[1];
        s1 += __shfl_xor(s1, 16, 64); s1 += __shfl_xor(s1, 32, 64);
        s2 += __shfl_xor(s2, 16, 64); s2 += __shfl_xor(s2, 32, 64);
        if (lq == 0) {
            float sg = (gd[u] < 0.f) ? -1.f : 1.f;
            float bdu = bd[u];
            m3[(size_t)k0 * 128 + u] = f2bf(fmaf(sg, mx0, bdu));
            m3[(size_t)(k0 + 1) * 128 + u] = f2bf(fmaf(sg, mx1, bdu));
            int slot = blockIdx.x & 63;
            atomicAdd(&slot3[slot * 256 + u], s1);
            atomicAdd(&slot3[slot * 256 + 128 + u], s2);
        }
    }
}

// ---------------------------------------------------------------------------
// Legacy phase A (r4 layout) for the recompute fallback paths
// ---------------------------------------------------------------------------
__device__ __forceinline__ void phaseA_leg(
    int k0, int tid,
    const float* __restrict__ x,
    const float* __restrict__ W1, const float* __restrict__ b1,
    const float* __restrict__ a1, const float* __restrict__ c1,
    ushort* __restrict__ h1, float* __restrict__ lmask, float* __restrict__ aggp) {
    int u = tid & 15;
    int g = tid >> 4;
    int v = g & 1;
    int th = g >> 1;
    float pmax = 0.f;
    if (th < 7) {
        float b1u = b1[u];
        float a1u = a1[u], c1u = c1[u];
        float w1c[7];
#pragma unroll
        for (int c = 0; c < 7; ++c) w1c[c] = W1[c * 16 + u];
#pragma unroll
        for (int i = 0; i < 5; ++i) {
            int t = th * 5 + i;
            const float* xp = x + ((size_t)(k0 + v) * TP + t) * 7;
            float xv[7];
            float sum7 = 0.f;
#pragma unroll
            for (int c = 0; c < 7; ++c) { xv[c] = xp[c]; sum7 += xv[c]; }
            float mkv = (sum7 != 0.f) ? 1.f : 0.f;
            if (u == 0) lmask[v * TP + t] = mkv;
            float val = b1u;
#pragma unroll
            for (int c = 0; c < 7; ++c) val = fmaf(xv[c], w1c[c], val);
            val = fmaxf(fmaf(a1u, val, c1u), 0.f);
            pmax = fmaxf(pmax, val);
            h1[(v * TP + t) * 40 + u] = f2bf(val * mkv);
        }
    } else {
#pragma unroll
        for (int i = 0; i < 5; ++i) {
            int row = 70 + (g & 1) * 5 + i;
            h1[row * 40 + u] = 0;
            if (u == 0) lmask[row] = 0.f;
        }
    }
    pmax = fmaxf(pmax, __shfl_xor(pmax, 32, 64));
    int w = tid >> 6;
    int lane = tid & 63;
    if (lane < 32) aggp[w * 32 + lane] = pmax;
    __syncthreads();
    {
        int uu = tid & 15;
        int r0 = tid >> 4;
        float g0 = fmaxf(fmaxf(aggp[uu], aggp[32 + uu]),
                         fmaxf(aggp[64 + uu], aggp[96 + uu]));
        float g1 = fmaxf(fmaxf(aggp[16 + uu], aggp[48 + uu]),
                         fmaxf(aggp[80 + uu], aggp[112 + uu]));
        ushort a0 = f2bf(g0), a1b = f2bf(g1);
#pragma unroll
        for (int j = 0; j < 5; ++j) {
            int row = r0 + j * 16;
            float mkv = lmask[row];
            h1[row * 40 + 16 + uu] = (mkv != 0.f) ? ((row < TP) ? a0 : a1b) : (ushort)0;
        }
    }
    __syncthreads();
}

// ---------------------------------------------------------------------------
// S3 fallback (recomputes phase A, 256 threads), r4 structure, sign-folded.
// ---------------------------------------------------------------------------
template <bool WSPATH>
__global__ __launch_bounds__(256) void k_stage3_full(
    const float* __restrict__ x,
    const float* __restrict__ W1, const float* __restrict__ b1,
    const float* __restrict__ b2,
    const ushort* __restrict__ w2t, const ushort* __restrict__ wdt,
    const float* __restrict__ bd, const float* __restrict__ gd,
    const float* __restrict__ ws,
    float* __restrict__ slot3,
    ushort* __restrict__ m3, float* __restrict__ outbuf) {
    __shared__ __align__(16) ushort h1[80 * 40];
    __shared__ __align__(16) ushort h2[80 * 136];
    __shared__ float lmask[80];
    __shared__ float aggp[128];
    __shared__ ushort agg2bf[128];
    int tid = threadIdx.x;
    int k0 = blockIdx.x * 2;
    int w = tid >> 6, lane = tid & 63, lq = lane >> 4, lr = lane & 15;
    phaseA_leg(k0, tid, x, W1, b1, ws + PAR_A1, ws + PAR_C1, h1, lmask, aggp);

    int u0 = w * 32;
    short8_t bfr[2][4];
#pragma unroll
    for (int s = 0; s < 2; ++s)
#pragma unroll
        for (int kk = 0; kk < 4; ++kk)
            bfr[s][kk] = *(const short8_t*)(wdt + ((u0 + s * 16 + lr) * 128 + kk * 32 + lq * 8));

    {
        int u = w * 16 + lr;
        short8_t bfrag = *(const short8_t*)(w2t + u * 32 + lq * 8);
        float a2u = ws[PAR_A2 + u];
        float c2p = fmaf(a2u, b2[u], ws[PAR_C2 + u]);
        float aggv0 = 0.f, aggv1 = 0.f;
#pragma unroll
        for (int mt = 0; mt < 5; ++mt) {
            short8_t afrag = *(const short8_t*)(h1 + (mt * 16 + lr) * 40 + lq * 8);
            f32x4 acc = {0.f, 0.f, 0.f, 0.f};
            acc = MFMA_BF16(afrag, bfrag, acc, 0, 0, 0);
#pragma unroll
            for (int r = 0; r < 4; ++r) {
                int m = mt * 16 + lq * 4 + r;
                float val = fmaxf(fmaf(a2u, acc[r], c2p), 0.f);
                float vm = (m < 70) ? val : 0.f;
                if (m < TP) aggv0 = fmaxf(aggv0, vm); else aggv1 = fmaxf(aggv1, vm);
                h2[m * 136 + u] = f2bf(val * lmask[m]);
            }
        }
        aggv0 = fmaxf(aggv0, __shfl_xor(aggv0, 16, 64));
        aggv0 = fmaxf(aggv0, __shfl_xor(aggv0, 32, 64));
        aggv1 = fmaxf(aggv1, __shfl_xor(aggv1, 16, 64));
        aggv1 = fmaxf(aggv1, __shfl_xor(aggv1, 32, 64));
        if (lq == 0) {
            agg2bf[u] = f2bf(aggv0);
            agg2bf[64 + u] = f2bf(aggv1);
        }
    }
    __syncthreads();
    {
        int c = tid & 63;
        int r0 = tid >> 6;
        ushort a0 = agg2bf[c], a1v = agg2bf[64 + c];
#pragma unroll
        for (int j = 0; j < 20; ++j) {
            int row = r0 + j * 4;
            float mkv = lmask[row];
            h2[row * 136 + 64 + c] = (mkv != 0.f) ? ((row < TP) ? a0 : a1v) : (ushort)0;
        }
    }
    __syncthreads();
    {
        float mxa[2][2], s1a[2], s2a[2];
#pragma unroll
        for (int s = 0; s < 2; ++s) {
            s1a[s] = 0.f; s2a[s] = 0.f;
            mxa[s][0] = -1e30f; mxa[s][1] = -1e30f;
        }
#pragma unroll
        for (int mt = 0; mt < 5; ++mt) {
            short8_t af[4];
#pragma unroll
            for (int kk = 0; kk < 4; ++kk)
                af[kk] = *(const short8_t*)(h2 + (mt * 16 + lr) * 136 + kk * 32 + lq * 8);
#pragma unroll
            for (int s = 0; s < 2; ++s) {
                f32x4 acc = {0.f, 0.f, 0.f, 0.f};
#pragma unroll
                for (int kk = 0; kk < 4; ++kk)
                    acc = MFMA_BF16(af[kk], bfr[s][kk], acc, 0, 0, 0);
#pragma unroll
                for (int r = 0; r < 4; ++r) {
                    float a = acc[r];
                    s1a[s] += a;
                    s2a[s] = fmaf(a, a, s2a[s]);
                    int m = mt * 16 + lq * 4 + r;
                    if (mt <= 1) mxa[s][0] = fmaxf(mxa[s][0], a);
                    else if (mt == 3) mxa[s][1] = fmaxf(mxa[s][1], a);
                    else if (mt == 2) { if (m < TP) mxa[s][0] = fmaxf(mxa[s][0], a); else mxa[s][1] = fmaxf(mxa[s][1], a); }
                    else { if (m < 70) mxa[s][1] = fmaxf(mxa[s][1], a); }
                }
            }
        }
#pragma unroll
        for (int s = 0; s < 2; ++s) {
#pragma unroll
            for (int v = 0; v < 2; ++v) {
                mxa[s][v] = fmaxf(mxa[s][v], __shfl_xor(mxa[s][v], 16, 64));
                mxa[s][v] = fmaxf(mxa[s][v], __shfl_xor(mxa[s][v], 32, 64));
            }
            s1a[s] += __shfl_xor(s1a[s], 16, 64); s1a[s] += __shfl_xor(s1a[s], 32, 64);
            s2a[s] += __shfl_xor(s2a[s], 16, 64); s2a[s] += __shfl_xor(s2a[s], 32, 64);
        }
        if (lq == 0) {
            int slot = blockIdx.x & 63;
#pragma unroll
            for (int s = 0; s < 2; ++s) {
                int u = u0 + s * 16 + lr;
                float bdu = bd[u];
                float sg = (gd[u] < 0.f) ? -1.f : 1.f;
#pragma unroll
                for (int v = 0; v < 2; ++v) {
                    float res = fmaf(sg, mxa[s][v], bdu);
                    if (WSPATH) m3[(size_t)(k0 + v) * 128 + u] = f2bf(res);
                    else        outbuf[(size_t)u * KVOX + (k0 + v)] = res;
                }
                atomicAdd(&slot3[slot * 256 + u], s1a[s]);
                atomicAdd(&slot3[slot * 256 + 128 + u], s2a[s]);
            }
        }
    }
}

// ---------------------------------------------------------------------------
// Finalize: out[u][k] = leaky(bn3(m3[k][u])) via LDS transpose (m3 = bf16)
// ---------------------------------------------------------------------------
__global__ __launch_bounds__(256) void k_final_ws(const ushort* __restrict__ m3,
                                                  const float* __restrict__ ws,
                                                  float* __restrict__ out) {
    __shared__ float tile[32][33];
    int tx = threadIdx.x & 31;
    int ty = threadIdx.x >> 5;
    int v0 = blockIdx.x * 32;
    int u0 = blockIdx.y * 32;
    const float* a3 = ws + PAR_A3;
    const float* c3 = ws + PAR_C3;
#pragma unroll
    for (int r = ty; r < 32; r += 8) {
        int v = v0 + r, u = u0 + tx;
        float y = 0.f;
        if (v < KVOX) {
            float a = a3[u], c = c3[u];
            float val = bf2f(m3[(size_t)v * 128 + u]);
            y = a * val + c;
            y = (y >= 0.f) ? y : 0.1f * y;
        }
        tile[r][tx] = y;
    }
    __syncthreads();
#pragma unroll
    for (int r = ty; r < 32; r += 8) {
        int u = u0 + r, v = v0 + tx;
        if (v < KVOX) out[(size_t)u * KVOX + v] = tile[tx][r];
    }
}

__global__ __launch_bounds__(256) void k_final_inplace(const float* __restrict__ ws,
                                                       float* __restrict__ out) {
    int v = blockIdx.x * 256 + threadIdx.x;
    int u = blockIdx.y;
    if (v >= KVOX) return;
    float a = ws[PAR_A3 + u], c = ws[PAR_C3 + u];
    size_t idx = (size_t)u * KVOX + v;
    float y = a * out[idx] + c;
    out[idx] = (y >= 0.f) ? y : 0.1f * y;
}

// ---------------------------------------------------------------------------
extern "C" void kernel_launch(void* const* d_in, const int* in_sizes, int n_in,
                              void* d_out, int out_size, void* d_ws, size_t ws_size,
                              hipStream_t stream) {
    const float* x   = (const float*)d_in[0];
    const void*  coord = d_in[1];
    const float* W1  = (const float*)d_in[3];
    const float* b1  = (const float*)d_in[4];
    const float* g1  = (const float*)d_in[5];
    const float* be1 = (const float*)d_in[6];
    const float* W2  = (const float*)d_in[7];
    const float* b2  = (const float*)d_in[8];
    const float* g2  = (const float*)d_in[9];
    const float* be2 = (const float*)d_in[10];
    const float* Wd  = (const float*)d_in[11];
    const float* bd  = (const float*)d_in[12];
    const float* gd  = (const float*)d_in[13];
    const float* bed = (const float*)d_in[14];
    float* ws = (float*)d_ws;
    float* out = (float*)d_out;
    ushort* w2t = (ushort*)(ws + W2T_OFF);
    ushort* wdt = (ushort*)(ws + WDT_OFF);
    ushort* m3  = (ushort*)(ws + M3_OFF);
    uint* recs  = (uint*)(ws + H1G_OFF);

    size_t wsf = ws_size / 4;
    bool full = wsf >= (size_t)FULL_FLOATS;
    bool small = wsf >= (size_t)SMALL_FLOATS;
    const float invN = 1.f / (float)NPTS;

    hipMemsetAsync(d_ws, 0, (size_t)STATS_FLOATS * 4, stream);

    k_prep_stats1<<<64 + 256, 256, 0, stream>>>(x, W2, Wd, gd, w2t, wdt, ws + SLOTG_OFF);
    k_affine1g<<<1, 64, 0, stream>>>(ws + SLOTG_OFF, W1, b1, g1, be1, ws + PAR_A1, ws + PAR_C1, invN);
    if (full)
        k_stats2<true><<<KVOX / 2, 256, 0, stream>>>(x, W1, b1, w2t, ws, ws + SLOT2_OFF, recs);
    else
        k_stats2<false><<<KVOX / 2, 256, 0, stream>>>(x, W1, b1, w2t, ws, ws + SLOT2_OFF, recs);
    k_affine_b<<<1, 64, 0, stream>>>(ws + SLOT2_OFF, g2, be2, b2, ws + PAR_A2, ws + PAR_C2, 64, invN);

    if (full) {
        k_stage3_reuse<<<KVOX / 2, 512, 0, stream>>>(recs, b2, w2t, wdt, bd, gd, ws,
                                                     ws + SLOT3_OFF, m3);
        k_affine_b3<<<1, 128, 0, stream>>>(ws + SLOT3_OFF, gd, bed, bd, ws + PAR_A3, ws + PAR_C3, 128, invN);
        k_final_ws<<<dim3((KVOX + 31) / 32, 4), 256, 0, stream>>>(m3, ws, out);
    } else if (small) {
        k_stage3_full<true><<<KVOX / 2, 256, 0, stream>>>(x, W1, b1, b2, w2t, wdt, bd, gd, ws,
                                                          ws + SLOT3_OFF, m3, out);
        k_affine_b3<<<1, 128, 0, stream>>>(ws + SLOT3_OFF, gd, bed, bd, ws + PAR_A3, ws + PAR_C3, 128, invN);
        k_final_ws<<<dim3((KVOX + 31) / 32, 4), 256, 0, stream>>>(m3, ws, out);
    } else {
        k_stage3_full<false><<<KVOX / 2, 256, 0, stream>>>(x, W1, b1, b2, w2t, wdt, bd, gd, ws,
                                                           ws + SLOT3_OFF, m3, out);
        k_affine_b3<<<1, 128, 0, stream>>>(ws + SLOT3_OFF, gd, bed, bd, ws + PAR_A3, ws + PAR_C3, 128, invN);
        k_final_inplace<<<dim3((KVOX + 255) / 256, 128), 256, 0, stream>>>(ws, out);
    }
    hipMemcpyAsync((char*)d_out + (size_t)128 * KVOX * 4, coord,
                   (size_t)KVOX * 4 * sizeof(int), hipMemcpyDeviceToDevice, stream);
}

// Round 6
// 154.022 us; speedup vs baseline: 8.1599x; 1.1446x over previous
//
#include <hip/hip_runtime.h>

#define KVOX 30000
#define TP 35
#define NPTS (KVOX * TP)
#define EPS_BN 1e-5f

typedef __attribute__((ext_vector_type(8))) short short8_t;   // 8 x bf16
typedef __attribute__((ext_vector_type(4))) float f32x4;

#define MFMA_BF16 __builtin_amdgcn_mfma_f32_16x16x32_bf16

// ---- ws layout (float offsets) ----
#define SLOTG_OFF 0                  // 64 x 40 (35 used: G[28] | Sx[7])
#define SLOT2_OFF 2560               // 64 x 128
#define SLOT3_OFF 10752              // 64 x 256
#define PAR_A1 27136
#define PAR_C1 27152
#define PAR_A2 27168
#define PAR_C2 27232
#define PAR_A3 27296
#define PAR_C3 27424
#define STATS_FLOATS 27136           // memset region: slots only
#define W2T_OFF 27552                // [64 u][32 k] bf16
#define WDT_OFF 28576                // [128 u][128 k] bf16 (sign-folded)
#define M3_OFF 36768                 // KVOX*128 bf16 = KVOX*64 floats
#define SMALL_FLOATS (36768 + KVOX * 64)
#define H1G_OFF SMALL_FLOATS         // per-4vox-block records
#define REC_DW 1224                  // 1120 h1(140rowsx16bf16) + 32 agg1 + 70 mask + 2 pad
#define FULL_FLOATS (H1G_OFF + (KVOX / 4) * REC_DW)

__device__ __forceinline__ ushort f2bf(float f) {
    uint r;
    asm("v_cvt_pk_bf16_f32 %0, %1, %2" : "=v"(r) : "v"(f), "v"(f));
    return (ushort)r;
}
__device__ __forceinline__ uint f2bf2(float lo, float hi) {
    uint r;
    asm("v_cvt_pk_bf16_f32 %0, %1, %2" : "=v"(r) : "v"(lo), "v"(hi));
    return r;
}
__device__ __forceinline__ float bf2f(ushort h) {
    union { uint u; float f; } v; v.u = ((uint)h) << 16; return v.f;
}

// ---------------------------------------------------------------------------
// prep (blocks 0..63): W2T; WDT with sign(gd) folded. stats1 (64+): Gram sums
// via f32x4 loads (4 points / 7 vec-loads per iteration).
// ---------------------------------------------------------------------------
__global__ __launch_bounds__(256) void k_prep_stats1(
    const float* __restrict__ x,
    const float* __restrict__ W2, const float* __restrict__ Wd,
    const float* __restrict__ gd,
    ushort* __restrict__ w2t, ushort* __restrict__ wdt,
    float* __restrict__ slotG) {
    if (blockIdx.x < 64) {
        int t = blockIdx.x * 256 + threadIdx.x;     // 0..16383
        if (t < 2048) {
            int u = t >> 5, k = t & 31;
            w2t[t] = f2bf(W2[k * 64 + u]);
        }
        int u = t >> 7, k = t & 127;
        float sg = (gd[u] < 0.f) ? -1.f : 1.f;
        wdt[t] = f2bf(Wd[k * 128 + u] * sg);
        return;
    }
    int bid = blockIdx.x - 64;                      // 0..255
    int tid = threadIdx.x;
    int gid = bid * 256 + tid;
    float sx[7], G[28];
#pragma unroll
    for (int c = 0; c < 7; ++c) sx[c] = 0.f;
#pragma unroll
    for (int i = 0; i < 28; ++i) G[i] = 0.f;
    for (size_t p4 = (size_t)gid * 4; p4 < NPTS; p4 += (size_t)65536 * 4) {
        const f32x4* xp = (const f32x4*)(x + p4 * 7);
        f32x4 q[7];
#pragma unroll
        for (int c = 0; c < 7; ++c) q[c] = xp[c];
#pragma unroll
        for (int j = 0; j < 4; ++j) {
            float xv[7];
#pragma unroll
            for (int c = 0; c < 7; ++c) {
                int idx = j * 7 + c;
                xv[c] = q[idx >> 2][idx & 3];
                sx[c] += xv[c];
            }
            int idx = 0;
#pragma unroll
            for (int i = 0; i < 7; ++i)
#pragma unroll
                for (int jj = i; jj < 7; ++jj) { G[idx] = fmaf(xv[i], xv[jj], G[idx]); ++idx; }
        }
    }
    int lane = tid & 63;
    int wv = tid >> 6;
    int slot = (bid * 4 + wv) & 63;
#pragma unroll
    for (int k = 0; k < 35; ++k) {
        float v = (k < 28) ? G[k] : sx[k - 28];
#pragma unroll
        for (int m = 32; m > 0; m >>= 1) v += __shfl_xor(v, m, 64);
        if (lane == 0) atomicAdd(&slotG[slot * 40 + k], v);
    }
}

// BN1 finalize from Gram stats
__global__ void k_affine1g(const float* __restrict__ slotG,
                           const float* __restrict__ W1, const float* __restrict__ b1,
                           const float* __restrict__ g1, const float* __restrict__ be1,
                           float* __restrict__ pa, float* __restrict__ pc, float invN) {
    __shared__ float red[35];
    int t = threadIdx.x;     // 64 threads
    if (t < 35) {
        float s = 0.f;
#pragma unroll
        for (int sl = 0; sl < 64; ++sl) s += slotG[sl * 40 + t];
        red[t] = s;
    }
    __syncthreads();
    if (t < 16) {
        float wv[7];
#pragma unroll
        for (int c = 0; c < 7; ++c) wv[c] = W1[c * 16 + t];
        float b = b1[t];
        float sw = 0.f;
#pragma unroll
        for (int c = 0; c < 7; ++c) sw = fmaf(red[28 + c], wv[c], sw);
        float gq = 0.f;
        int idx = 0;
#pragma unroll
        for (int i = 0; i < 7; ++i)
#pragma unroll
            for (int j = i; j < 7; ++j) {
                float coef = wv[i] * wv[j];
                if (i != j) coef *= 2.f;
                gq = fmaf(coef, red[idx], gq);
                ++idx;
            }
        float mr = sw * invN;
        float mean = mr + b;
        float ex2 = gq * invN + 2.f * b * mr + b * b;
        float var = ex2 - mean * mean;
        float av = g1[t] * rsqrtf(var + EPS_BN);
        pa[t] = av;
        pc[t] = be1[t] - mean * av;
    }
}

// Bias-folded BN finalize: slots hold sums of (pw - b)
__global__ void k_affine_b(const float* __restrict__ slots,
                           const float* __restrict__ g,
                           const float* __restrict__ be,
                           const float* __restrict__ bias,
                           float* __restrict__ pa, float* __restrict__ pc,
                           int C, float invN) {
    int u = threadIdx.x;
    if (u >= C) return;
    float s = 0.f, q = 0.f;
    for (int sl = 0; sl < 64; ++sl) {
        s += slots[sl * 2 * C + u];
        q += slots[sl * 2 * C + C + u];
    }
    float b = bias[u];
    float mr = s * invN;
    float mean = mr + b;
    float ex2 = q * invN + 2.f * b * mr + b * b;
    float var = ex2 - mean * mean;
    float av = g[u] * rsqrtf(var + EPS_BN);
    pa[u] = av;
    pc[u] = be[u] - mean * av;
}

// Sign-aware variant for BN3: slots hold sums of sgn(g)*(pw - b)
__global__ void k_affine_b3(const float* __restrict__ slots,
                            const float* __restrict__ g,
                            const float* __restrict__ be,
                            const float* __restrict__ bias,
                            float* __restrict__ pa, float* __restrict__ pc,
                            int C, float invN) {
    int u = threadIdx.x;
    if (u >= C) return;
    float s = 0.f, q = 0.f;
    for (int sl = 0; sl < 64; ++sl) {
        s += slots[sl * 2 * C + u];
        q += slots[sl * 2 * C + C + u];
    }
    float sg = (g[u] < 0.f) ? -1.f : 1.f;
    s *= sg;
    float b = bias[u];
    float mr = s * invN;
    float mean = mr + b;
    float ex2 = q * invN + 2.f * b * mr + b * b;
    float var = ex2 - mean * mean;
    float av = g[u] * rsqrtf(var + EPS_BN);
    pa[u] = av;
    pc[u] = be[u] - mean * av;
}

// ---------------------------------------------------------------------------
// Phase A, 4 voxels, 512 threads. Rows = 4t+v (140 real + 4 pad = 144).
// h1 bf16 [144][24] masked (cols 0..15). agg1bf [4][16] bf16. lmask[144] f32.
// ---------------------------------------------------------------------------
__device__ __forceinline__ void phaseA4(
    int k0, int tid,
    const float* __restrict__ x,
    const float* __restrict__ W1, const float* __restrict__ b1,
    const float* __restrict__ a1, const float* __restrict__ c1,
    ushort* __restrict__ h1, float* __restrict__ lmask,
    float* __restrict__ aggp /*[7*64]*/, ushort* __restrict__ agg1bf /*[64]*/) {
    int u = tid & 15;
    int g = tid >> 4;      // 0..31
    int v = g & 3;
    int th = g >> 2;       // 0..7
    float pmax = 0.f;
    if (th < 7) {
        float b1u = b1[u];
        float a1u = a1[u], c1u = c1[u];
        float w1c[7];
#pragma unroll
        for (int c = 0; c < 7; ++c) w1c[c] = W1[c * 16 + u];
#pragma unroll
        for (int i = 0; i < 5; ++i) {
            int t = th * 5 + i;
            const float* xp = x + ((size_t)(k0 + v) * TP + t) * 7;
            float xv[7];
            float sum7 = 0.f;
#pragma unroll
            for (int c = 0; c < 7; ++c) { xv[c] = xp[c]; sum7 += xv[c]; }
            float mkv = (sum7 != 0.f) ? 1.f : 0.f;
            int row = 4 * t + v;
            if (u == 0) lmask[row] = mkv;
            float val = b1u;
#pragma unroll
            for (int c = 0; c < 7; ++c) val = fmaf(xv[c], w1c[c], val);
            val = fmaxf(fmaf(a1u, val, c1u), 0.f);
            pmax = fmaxf(pmax, val);                 // unmasked (ref semantics)
            h1[row * 24 + u] = f2bf(val * mkv);
        }
    } else {
        // wave 7: zero pad rows 140..143
        int row = 140 + v;
        h1[row * 24 + u] = 0;
        if (u == 0) lmask[row] = 0.f;
    }
    int w = tid >> 6;
    int lane = tid & 63;                              // lane = v*16+u
    if (w < 7) aggp[w * 64 + lane] = pmax;
    __syncthreads();
    if (tid < 64) {
        float m = aggp[tid];
#pragma unroll
        for (int ww = 1; ww < 7; ++ww) m = fmaxf(m, aggp[ww * 64 + tid]);
        agg1bf[tid] = f2bf(m);                        // layout [v*16+u]
    }
    __syncthreads();
}

// ---------------------------------------------------------------------------
// S2: BN2 stats via rank-1 MFMA (4 voxels, 512 thr); dumps record if DUMP.
// ---------------------------------------------------------------------------
template <bool DUMP>
__global__ __launch_bounds__(512, 8) void k_stats2(
    const float* __restrict__ x,
    const float* __restrict__ W1, const float* __restrict__ b1,
    const ushort* __restrict__ w2t,
    const float* __restrict__ ws,
    float* __restrict__ slot2, uint* __restrict__ recs) {
    __shared__ __align__(16) ushort h1[144 * 24];
    __shared__ float lmask[144];
    __shared__ float aggp[7 * 64];
    __shared__ __align__(16) ushort agg1bf[64];
    __shared__ __align__(16) uint zeros16[4];
    int tid = threadIdx.x;
    int k0 = blockIdx.x * 4;
    if (tid < 4) zeros16[tid] = 0;
    phaseA4(k0, tid, x, W1, b1, ws + PAR_A1, ws + PAR_C1, h1, lmask, aggp, agg1bf);
    if (DUMP) {
        uint* rec = recs + (size_t)blockIdx.x * REC_DW;
        const uint* h1dw = (const uint*)h1;
        for (int i = tid; i < 1120; i += 512) rec[i] = h1dw[(i >> 3) * 12 + (i & 7)];
        if (tid < 32) rec[1120 + tid] = ((const uint*)agg1bf)[tid];
        if (tid < 70) rec[1152 + tid] = f2bf2(lmask[2 * tid], lmask[2 * tid + 1]);
    }
    int w = tid >> 6, lane = tid & 63, lq = lane >> 4, lr = lane & 15;
    int mh = w >> 2, uq = w & 3;
    int u = uq * 16 + lr;
    short8_t bB = *(const short8_t*)(w2t + u * 32 + (lq & 1) * 8);
    short8_t bP = *(const short8_t*)(w2t + u * 32 + 16 + (lq & 1) * 8);
    const ushort* pap = (lq < 2) ? (agg1bf + (lr & 3) * 16 + (lq & 1) * 8) : (const ushort*)zeros16;
    short8_t pAf = *(const short8_t*)pap;
    f32x4 aP = {0.f, 0.f, 0.f, 0.f};
    aP = MFMA_BF16(pAf, bP, aP, 0, 0, 0);
    f32x4 p1;
    p1[0] = __shfl(aP[0], lr, 64); p1[1] = __shfl(aP[1], lr, 64);
    p1[2] = __shfl(aP[2], lr, 64); p1[3] = __shfl(aP[3], lr, 64);
    f32x4 s1p = {0.f, 0.f, 0.f, 0.f}, s2p = {0.f, 0.f, 0.f, 0.f};
    int mt0 = mh ? 5 : 0, mt1 = mh ? 9 : 5;
    for (int mt = mt0; mt < mt1; ++mt) {
        const ushort* ha = (lq < 2) ? (h1 + (mt * 16 + lr) * 24 + (lq & 1) * 8) : (const ushort*)zeros16;
        short8_t af = *(const short8_t*)ha;
        f32x4 acc = {0.f, 0.f, 0.f, 0.f};
        acc = MFMA_BF16(af, bB, acc, 0, 0, 0);
        f32x4 mk = *(const f32x4*)(lmask + mt * 16 + lq * 4);
        f32x4 am = (acc + p1) * mk;
        s1p += am;
        s2p += am * am;
    }
    float s1 = s1p[0] + s1p[1] + s1p[2] + s1p[3];
    float s2 = s2p[0] + s2p[1] + s2p[2] + s2p[3];
    s1 += __shfl_xor(s1, 16, 64); s1 += __shfl_xor(s1, 32, 64);
    s2 += __shfl_xor(s2, 16, 64); s2 += __shfl_xor(s2, 32, 64);
    if (lq == 0) {
        int slot = blockIdx.x & 63;
        atomicAdd(&slot2[slot * 128 + u], s1);
        atomicAdd(&slot2[slot * 128 + 64 + u], s2);
    }
}

// ---------------------------------------------------------------------------
// S3 REUSE: 4 voxels, 512 thr. Stage record -> phase B (atomicMax agg2 via
// uint bits, kills pack barrier) -> phase C. Only 2 barriers per block.
// ---------------------------------------------------------------------------
__global__ __launch_bounds__(512, 8) void k_stage3_reuse(
    const uint* __restrict__ recs,
    const float* __restrict__ b2,
    const ushort* __restrict__ w2t, const ushort* __restrict__ wdt,
    const float* __restrict__ bd, const float* __restrict__ gd,
    const float* __restrict__ ws,
    float* __restrict__ slot3, ushort* __restrict__ m3) {
    __shared__ __align__(16) ushort h1[144 * 24];
    __shared__ __align__(16) ushort h2[144 * 72];
    __shared__ float lmask[144];
    __shared__ __align__(16) uint aggfU[4 * 68];     // [vox][68] f32-bits (max)
    __shared__ __align__(16) ushort agg1bf[64];
    __shared__ __align__(16) uint zeros16[4];
    int tid = threadIdx.x;
    int k0 = blockIdx.x * 4;
    int w = tid >> 6, lane = tid & 63, lq = lane >> 4, lr = lane & 15;

    // ---- staging ----
    {
        const uint* rec = recs + (size_t)blockIdx.x * REC_DW;
        uint* h1dw = (uint*)h1;
        {
            int i = tid;              h1dw[(i >> 3) * 12 + (i & 7)] = rec[i];
            i = tid + 512;            h1dw[(i >> 3) * 12 + (i & 7)] = rec[i];
            i = tid + 1024; if (i < 1120) h1dw[(i >> 3) * 12 + (i & 7)] = rec[i];
        }
        if (tid < 48) h1dw[140 * 12 + tid] = 0u;     // pad rows 140..143
        if (tid < 32) ((uint*)agg1bf)[tid] = rec[1120 + tid];
        if (tid < 72) {
            if (tid < 70) {
                uint mw = rec[1152 + tid];
                lmask[2 * tid] = bf2f((ushort)(mw & 0xffffu));
                lmask[2 * tid + 1] = bf2f((ushort)(mw >> 16));
            } else {
                int j = 140 + (tid - 70) * 2;
                lmask[j] = 0.f; lmask[j + 1] = 0.f;
            }
        }
        if (tid < 272) aggfU[tid] = 0u;
        if (tid < 4) zeros16[tid] = 0u;
    }
    __syncthreads();

    // ---- phase B: waves (mh = rows half, uq = u quarter); vox = acc slot r ----
    {
        int mh = w >> 2, uq = w & 3;
        int u = uq * 16 + lr;
        short8_t bB = *(const short8_t*)(w2t + u * 32 + (lq & 1) * 8);
        short8_t bP = *(const short8_t*)(w2t + u * 32 + 16 + (lq & 1) * 8);
        const ushort* pap = (lq < 2) ? (agg1bf + (lr & 3) * 16 + (lq & 1) * 8) : (const ushort*)zeros16;
        short8_t pAf = *(const short8_t*)pap;
        f32x4 aP = {0.f, 0.f, 0.f, 0.f};
        aP = MFMA_BF16(pAf, bP, aP, 0, 0, 0);
        f32x4 p1;
        p1[0] = __shfl(aP[0], lr, 64); p1[1] = __shfl(aP[1], lr, 64);
        p1[2] = __shfl(aP[2], lr, 64); p1[3] = __shfl(aP[3], lr, 64);
        float a2u = ws[PAR_A2 + u];
        float c2u = fmaf(a2u, b2[u], ws[PAR_C2 + u]);
        f32x4 av = {0.f, 0.f, 0.f, 0.f};
        int mt0 = mh ? 5 : 0, mt1 = mh ? 9 : 5;
        for (int mt = mt0; mt < mt1; ++mt) {
            const ushort* ha = (lq < 2) ? (h1 + (mt * 16 + lr) * 24 + (lq & 1) * 8) : (const ushort*)zeros16;
            short8_t af = *(const short8_t*)ha;
            f32x4 acc = {0.f, 0.f, 0.f, 0.f};
            acc = MFMA_BF16(af, bB, acc, 0, 0, 0);
            f32x4 mk = *(const f32x4*)(lmask + mt * 16 + lq * 4);
            int m0 = mt * 16 + lq * 4;
            f32x4 vals;
#pragma unroll
            for (int r = 0; r < 4; ++r) {
                float am = (acc[r] + p1[r]) * mk[r];
                float val = fmaxf(fmaf(a2u, am, c2u), 0.f);
                h2[(m0 + r) * 72 + u] = f2bf(val);
                vals[r] = val;
            }
            if (!(mt == 8 && lq == 3)) {             // exclude pad rows 140..143
#pragma unroll
                for (int r = 0; r < 4; ++r) av[r] = fmaxf(av[r], vals[r]);
            }
        }
#pragma unroll
        for (int r = 0; r < 4; ++r) {
            av[r] = fmaxf(av[r], __shfl_xor(av[r], 16, 64));
            av[r] = fmaxf(av[r], __shfl_xor(av[r], 32, 64));
        }
        if (lq == 0) {
#pragma unroll
            for (int r = 0; r < 4; ++r)
                atomicMax(&aggfU[r * 68 + u], __float_as_uint(av[r]));
        }
    }
    __syncthreads();

    // ---- phase C: pw3 = h2@Wd[0:64] + mask*proj2(agg2) ----
    {
        int u = w * 16 + lr;
        short8_t bM0 = *(const short8_t*)(wdt + u * 128 + lq * 8);
        short8_t bM1 = *(const short8_t*)(wdt + u * 128 + 32 + lq * 8);
        short8_t bP0 = *(const short8_t*)(wdt + u * 128 + 64 + lq * 8);
        short8_t bP1 = *(const short8_t*)(wdt + u * 128 + 96 + lq * 8);
        const float* aggf = (const float*)aggfU;
        f32x4 q0 = *(const f32x4*)(aggf + (lr & 3) * 68 + lq * 8);
        f32x4 q1 = *(const f32x4*)(aggf + (lr & 3) * 68 + lq * 8 + 4);
        f32x4 q2 = *(const f32x4*)(aggf + (lr & 3) * 68 + 32 + lq * 8);
        f32x4 q3 = *(const f32x4*)(aggf + (lr & 3) * 68 + 32 + lq * 8 + 4);
        union { uint uu[4]; short8_t s8; } pc0, pc1;
        pc0.uu[0] = f2bf2(q0[0], q0[1]); pc0.uu[1] = f2bf2(q0[2], q0[3]);
        pc0.uu[2] = f2bf2(q1[0], q1[1]); pc0.uu[3] = f2bf2(q1[2], q1[3]);
        pc1.uu[0] = f2bf2(q2[0], q2[1]); pc1.uu[1] = f2bf2(q2[2], q2[3]);
        pc1.uu[2] = f2bf2(q3[0], q3[1]); pc1.uu[3] = f2bf2(q3[2], q3[3]);
        f32x4 aP = {0.f, 0.f, 0.f, 0.f};
        aP = MFMA_BF16(pc0.s8, bP0, aP, 0, 0, 0);
        aP = MFMA_BF16(pc1.s8, bP1, aP, 0, 0, 0);
        f32x4 p2;
        p2[0] = __shfl(aP[0], lr, 64); p2[1] = __shfl(aP[1], lr, 64);
        p2[2] = __shfl(aP[2], lr, 64); p2[3] = __shfl(aP[3], lr, 64);
        f32x4 s1p = {0.f, 0.f, 0.f, 0.f}, s2p = {0.f, 0.f, 0.f, 0.f};
        f32x4 mx = {-1e30f, -1e30f, -1e30f, -1e30f};
#pragma unroll
        for (int mt = 0; mt < 9; ++mt) {
            const ushort* hrow = h2 + (mt * 16 + lr) * 72;
            short8_t a0 = *(const short8_t*)(hrow + lq * 8);
            short8_t a1 = *(const short8_t*)(hrow + 32 + lq * 8);
            f32x4 acc = {0.f, 0.f, 0.f, 0.f};
            acc = MFMA_BF16(a0, bM0, acc, 0, 0, 0);
            acc = MFMA_BF16(a1, bM1, acc, 0, 0, 0);
            f32x4 mk = *(const f32x4*)(lmask + mt * 16 + lq * 4);
            f32x4 am = (acc + p2) * mk;
            s1p += am;
            s2p += am * am;
            if (mt < 8) {
#pragma unroll
                for (int r = 0; r < 4; ++r) mx[r] = fmaxf(mx[r], am[r]);
            } else if (lq < 3) {                     // rows 128..139 only
#pragma unroll
                for (int r = 0; r < 4; ++r) mx[r] = fmaxf(mx[r], am[r]);
            }
        }
#pragma unroll
        for (int r = 0; r < 4; ++r) {
            mx[r] = fmaxf(mx[r], __shfl_xor(mx[r], 16, 64));
            mx[r] = fmaxf(mx[r], __shfl_xor(mx[r], 32, 64));
        }
        float s1 = s1p[0] + s1p[1] + s1p[2] + s1p[3];
        float s2 = s2p[0] + s2p[1] + s2p[2] + s2p[3];
        s1 += __shfl_xor(s1, 16, 64); s1 += __shfl_xor(s1, 32, 64);
        s2 += __shfl_xor(s2, 16, 64); s2 += __shfl_xor(s2, 32, 64);
        if (lq == 0) {
            float sg = (gd[u] < 0.f) ? -1.f : 1.f;
            float bdu = bd[u];
#pragma unroll
            for (int r = 0; r < 4; ++r)
                m3[(size_t)(k0 + r) * 128 + u] = f2bf(fmaf(sg, mx[r], bdu));
            int slot = blockIdx.x & 63;
            atomicAdd(&slot3[slot * 256 + u], s1);
            atomicAdd(&slot3[slot * 256 + 128 + u], s2);
        }
    }
}

// ---------------------------------------------------------------------------
// Legacy 2-vox phase A + full-recompute fallback (small / tiny ws tiers)
// ---------------------------------------------------------------------------
__device__ __forceinline__ void phaseA_leg(
    int k0, int tid,
    const float* __restrict__ x,
    const float* __restrict__ W1, const float* __restrict__ b1,
    const float* __restrict__ a1, const float* __restrict__ c1,
    ushort* __restrict__ h1, float* __restrict__ lmask, float* __restrict__ aggp) {
    int u = tid & 15;
    int g = tid >> 4;
    int v = g & 1;
    int th = g >> 1;
    float pmax = 0.f;
    if (th < 7) {
        float b1u = b1[u];
        float a1u = a1[u], c1u = c1[u];
        float w1c[7];
#pragma unroll
        for (int c = 0; c < 7; ++c) w1c[c] = W1[c * 16 + u];
#pragma unroll
        for (int i = 0; i < 5; ++i) {
            int t = th * 5 + i;
            const float* xp = x + ((size_t)(k0 + v) * TP + t) * 7;
            float xv[7];
            float sum7 = 0.f;
#pragma unroll
            for (int c = 0; c < 7; ++c) { xv[c] = xp[c]; sum7 += xv[c]; }
            float mkv = (sum7 != 0.f) ? 1.f : 0.f;
            if (u == 0) lmask[v * TP + t] = mkv;
            float val = b1u;
#pragma unroll
            for (int c = 0; c < 7; ++c) val = fmaf(xv[c], w1c[c], val);
            val = fmaxf(fmaf(a1u, val, c1u), 0.f);
            pmax = fmaxf(pmax, val);
            h1[(v * TP + t) * 40 + u] = f2bf(val * mkv);
        }
    } else {
#pragma unroll
        for (int i = 0; i < 5; ++i) {
            int row = 70 + (g & 1) * 5 + i;
            h1[row * 40 + u] = 0;
            if (u == 0) lmask[row] = 0.f;
        }
    }
    pmax = fmaxf(pmax, __shfl_xor(pmax, 32, 64));
    int w = tid >> 6;
    int lane = tid & 63;
    if (lane < 32) aggp[w * 32 + lane] = pmax;
    __syncthreads();
    {
        int uu = tid & 15;
        int r0 = tid >> 4;
        float g0 = fmaxf(fmaxf(aggp[uu], aggp[32 + uu]),
                         fmaxf(aggp[64 + uu], aggp[96 + uu]));
        float g1 = fmaxf(fmaxf(aggp[16 + uu], aggp[48 + uu]),
                         fmaxf(aggp[80 + uu], aggp[112 + uu]));
        ushort a0 = f2bf(g0), a1b = f2bf(g1);
#pragma unroll
        for (int j = 0; j < 5; ++j) {
            int row = r0 + j * 16;
            float mkv = lmask[row];
            h1[row * 40 + 16 + uu] = (mkv != 0.f) ? ((row < TP) ? a0 : a1b) : (ushort)0;
        }
    }
    __syncthreads();
}

template <bool WSPATH>
__global__ __launch_bounds__(256) void k_stage3_full(
    const float* __restrict__ x,
    const float* __restrict__ W1, const float* __restrict__ b1,
    const float* __restrict__ b2,
    const ushort* __restrict__ w2t, const ushort* __restrict__ wdt,
    const float* __restrict__ bd, const float* __restrict__ gd,
    const float* __restrict__ ws,
    float* __restrict__ slot3,
    ushort* __restrict__ m3, float* __restrict__ outbuf) {
    __shared__ __align__(16) ushort h1[80 * 40];
    __shared__ __align__(16) ushort h2[80 * 136];
    __shared__ float lmask[80];
    __shared__ float aggp[128];
    __shared__ ushort agg2bf[128];
    int tid = threadIdx.x;
    int k0 = blockIdx.x * 2;
    int w = tid >> 6, lane = tid & 63, lq = lane >> 4, lr = lane & 15;
    phaseA_leg(k0, tid, x, W1, b1, ws + PAR_A1, ws + PAR_C1, h1, lmask, aggp);

    int u0 = w * 32;
    short8_t bfr[2][4];
#pragma unroll
    for (int s = 0; s < 2; ++s)
#pragma unroll
        for (int kk = 0; kk < 4; ++kk)
            bfr[s][kk] = *(const short8_t*)(wdt + ((u0 + s * 16 + lr) * 128 + kk * 32 + lq * 8));

    {
        int u = w * 16 + lr;
        short8_t bfrag = *(const short8_t*)(w2t + u * 32 + lq * 8);
        float a2u = ws[PAR_A2 + u];
        float c2p = fmaf(a2u, b2[u], ws[PAR_C2 + u]);
        float aggv0 = 0.f, aggv1 = 0.f;
#pragma unroll
        for (int mt = 0; mt < 5; ++mt) {
            short8_t afrag = *(const short8_t*)(h1 + (mt * 16 + lr) * 40 + lq * 8);
            f32x4 acc = {0.f, 0.f, 0.f, 0.f};
            acc = MFMA_BF16(afrag, bfrag, acc, 0, 0, 0);
#pragma unroll
            for (int r = 0; r < 4; ++r) {
                int m = mt * 16 + lq * 4 + r;
                float val = fmaxf(fmaf(a2u, acc[r], c2p), 0.f);
                float vm = (m < 70) ? val : 0.f;
                if (m < TP) aggv0 = fmaxf(aggv0, vm); else aggv1 = fmaxf(aggv1, vm);
                h2[m * 136 + u] = f2bf(val * lmask[m]);
            }
        }
        aggv0 = fmaxf(aggv0, __shfl_xor(aggv0, 16, 64));
        aggv0 = fmaxf(aggv0, __shfl_xor(aggv0, 32, 64));
        aggv1 = fmaxf(aggv1, __shfl_xor(aggv1, 16, 64));
        aggv1 = fmaxf(aggv1, __shfl_xor(aggv1, 32, 64));
        if (lq == 0) {
            agg2bf[u] = f2bf(aggv0);
            agg2bf[64 + u] = f2bf(aggv1);
        }
    }
    __syncthreads();
    {
        int c = tid & 63;
        int r0 = tid >> 6;
        ushort a0 = agg2bf[c], a1v = agg2bf[64 + c];
#pragma unroll
        for (int j = 0; j < 20; ++j) {
            int row = r0 + j * 4;
            float mkv = lmask[row];
            h2[row * 136 + 64 + c] = (mkv != 0.f) ? ((row < TP) ? a0 : a1v) : (ushort)0;
        }
    }
    __syncthreads();
    {
        float mxa[2][2], s1a[2], s2a[2];
#pragma unroll
        for (int s = 0; s < 2; ++s) {
            s1a[s] = 0.f; s2a[s] = 0.f;
            mxa[s][0] = -1e30f; mxa[s][1] = -1e30f;
        }
#pragma unroll
        for (int mt = 0; mt < 5; ++mt) {
            short8_t af[4];
#pragma unroll
            for (int kk = 0; kk < 4; ++kk)
                af[kk] = *(const short8_t*)(h2 + (mt * 16 + lr) * 136 + kk * 32 + lq * 8);
#pragma unroll
            for (int s = 0; s < 2; ++s) {
                f32x4 acc = {0.f, 0.f, 0.f, 0.f};
#pragma unroll
                for (int kk = 0; kk < 4; ++kk)
                    acc = MFMA_BF16(af[kk], bfr[s][kk], acc, 0, 0, 0);
#pragma unroll
                for (int r = 0; r < 4; ++r) {
                    float a = acc[r];
                    s1a[s] += a;
                    s2a[s] = fmaf(a, a, s2a[s]);
                    int m = mt * 16 + lq * 4 + r;
                    if (mt <= 1) mxa[s][0] = fmaxf(mxa[s][0], a);
                    else if (mt == 3) mxa[s][1] = fmaxf(mxa[s][1], a);
                    else if (mt == 2) { if (m < TP) mxa[s][0] = fmaxf(mxa[s][0], a); else mxa[s][1] = fmaxf(mxa[s][1], a); }
                    else { if (m < 70) mxa[s][1] = fmaxf(mxa[s][1], a); }
                }
            }
        }
#pragma unroll
        for (int s = 0; s < 2; ++s) {
#pragma unroll
            for (int v = 0; v < 2; ++v) {
                mxa[s][v] = fmaxf(mxa[s][v], __shfl_xor(mxa[s][v], 16, 64));
                mxa[s][v] = fmaxf(mxa[s][v], __shfl_xor(mxa[s][v], 32, 64));
            }
            s1a[s] += __shfl_xor(s1a[s], 16, 64); s1a[s] += __shfl_xor(s1a[s], 32, 64);
            s2a[s] += __shfl_xor(s2a[s], 16, 64); s2a[s] += __shfl_xor(s2a[s], 32, 64);
        }
        if (lq == 0) {
            int slot = blockIdx.x & 63;
#pragma unroll
            for (int s = 0; s < 2; ++s) {
                int u = u0 + s * 16 + lr;
                float bdu = bd[u];
                float sg = (gd[u] < 0.f) ? -1.f : 1.f;
#pragma unroll
                for (int v = 0; v < 2; ++v) {
                    float res = fmaf(sg, mxa[s][v], bdu);
                    if (WSPATH) m3[(size_t)(k0 + v) * 128 + u] = f2bf(res);
                    else        outbuf[(size_t)u * KVOX + (k0 + v)] = res;
                }
                atomicAdd(&slot3[slot * 256 + u], s1a[s]);
                atomicAdd(&slot3[slot * 256 + 128 + u], s2a[s]);
            }
        }
    }
}

// ---------------------------------------------------------------------------
// Finalize: out[u][k] = leaky(bn3(m3[k][u])) via LDS transpose (m3 = bf16)
// ---------------------------------------------------------------------------
__global__ __launch_bounds__(256) void k_final_ws(const ushort* __restrict__ m3,
                                                  const float* __restrict__ ws,
                                                  float* __restrict__ out) {
    __shared__ float tile[32][33];
    int tx = threadIdx.x & 31;
    int ty = threadIdx.x >> 5;
    int v0 = blockIdx.x * 32;
    int u0 = blockIdx.y * 32;
    const float* a3 = ws + PAR_A3;
    const float* c3 = ws + PAR_C3;
#pragma unroll
    for (int r = ty; r < 32; r += 8) {
        int v = v0 + r, u = u0 + tx;
        float y = 0.f;
        if (v < KVOX) {
            float a = a3[u], c = c3[u];
            float val = bf2f(m3[(size_t)v * 128 + u]);
            y = a * val + c;
            y = (y >= 0.f) ? y : 0.1f * y;
        }
        tile[r][tx] = y;
    }
    __syncthreads();
#pragma unroll
    for (int r = ty; r < 32; r += 8) {
        int u = u0 + r, v = v0 + tx;
        if (v < KVOX) out[(size_t)u * KVOX + v] = tile[tx][r];
    }
}

__global__ __launch_bounds__(256) void k_final_inplace(const float* __restrict__ ws,
                                                       float* __restrict__ out) {
    int v = blockIdx.x * 256 + threadIdx.x;
    int u = blockIdx.y;
    if (v >= KVOX) return;
    float a = ws[PAR_A3 + u], c = ws[PAR_C3 + u];
    size_t idx = (size_t)u * KVOX + v;
    float y = a * out[idx] + c;
    out[idx] = (y >= 0.f) ? y : 0.1f * y;
}

// ---------------------------------------------------------------------------
extern "C" void kernel_launch(void* const* d_in, const int* in_sizes, int n_in,
                              void* d_out, int out_size, void* d_ws, size_t ws_size,
                              hipStream_t stream) {
    const float* x   = (const float*)d_in[0];
    const void*  coord = d_in[1];
    const float* W1  = (const float*)d_in[3];
    const float* b1  = (const float*)d_in[4];
    const float* g1  = (const float*)d_in[5];
    const float* be1 = (const float*)d_in[6];
    const float* W2  = (const float*)d_in[7];
    const float* b2  = (const float*)d_in[8];
    const float* g2  = (const float*)d_in[9];
    const float* be2 = (const float*)d_in[10];
    const float* Wd  = (const float*)d_in[11];
    const float* bd  = (const float*)d_in[12];
    const float* gd  = (const float*)d_in[13];
    const float* bed = (const float*)d_in[14];
    float* ws = (float*)d_ws;
    float* out = (float*)d_out;
    ushort* w2t = (ushort*)(ws + W2T_OFF);
    ushort* wdt = (ushort*)(ws + WDT_OFF);
    ushort* m3  = (ushort*)(ws + M3_OFF);
    uint* recs  = (uint*)(ws + H1G_OFF);

    size_t wsf = ws_size / 4;
    bool full = wsf >= (size_t)FULL_FLOATS;
    bool small = wsf >= (size_t)SMALL_FLOATS;
    const float invN = 1.f / (float)NPTS;

    hipMemsetAsync(d_ws, 0, (size_t)STATS_FLOATS * 4, stream);

    k_prep_stats1<<<64 + 256, 256, 0, stream>>>(x, W2, Wd, gd, w2t, wdt, ws + SLOTG_OFF);
    k_affine1g<<<1, 64, 0, stream>>>(ws + SLOTG_OFF, W1, b1, g1, be1, ws + PAR_A1, ws + PAR_C1, invN);
    if (full)
        k_stats2<true><<<KVOX / 4, 512, 0, stream>>>(x, W1, b1, w2t, ws, ws + SLOT2_OFF, recs);
    else
        k_stats2<false><<<KVOX / 4, 512, 0, stream>>>(x, W1, b1, w2t, ws, ws + SLOT2_OFF, recs);
    k_affine_b<<<1, 64, 0, stream>>>(ws + SLOT2_OFF, g2, be2, b2, ws + PAR_A2, ws + PAR_C2, 64, invN);

    if (full) {
        k_stage3_reuse<<<KVOX / 4, 512, 0, stream>>>(recs, b2, w2t, wdt, bd, gd, ws,
                                                     ws + SLOT3_OFF, m3);
        k_affine_b3<<<1, 128, 0, stream>>>(ws + SLOT3_OFF, gd, bed, bd, ws + PAR_A3, ws + PAR_C3, 128, invN);
        k_final_ws<<<dim3((KVOX + 31) / 32, 4), 256, 0, stream>>>(m3, ws, out);
    } else if (small) {
        k_stage3_full<true><<<KVOX / 2, 256, 0, stream>>>(x, W1, b1, b2, w2t, wdt, bd, gd, ws,
                                                          ws + SLOT3_OFF, m3, out);
        k_affine_b3<<<1, 128, 0, stream>>>(ws + SLOT3_OFF, gd, bed, bd, ws + PAR_A3, ws + PAR_C3, 128, invN);
        k_final_ws<<<dim3((KVOX + 31) / 32, 4), 256, 0, stream>>>(m3, ws, out);
    } else {
        k_stage3_full<false><<<KVOX / 2, 256, 0, stream>>>(x, W1, b1, b2, w2t, wdt, bd, gd, ws,
                                                           ws + SLOT3_OFF, m3, out);
        k_affine_b3<<<1, 128, 0, stream>>>(ws + SLOT3_OFF, gd, bed, bd, ws + PAR_A3, ws + PAR_C3, 128, invN);
        k_final_inplace<<<dim3((KVOX + 255) / 256, 128), 256, 0, stream>>>(ws, out);
    }
    hipMemcpyAsync((char*)d_out + (size_t)128 * KVOX * 4, coord,
                   (size_t)KVOX * 4 * sizeof(int), hipMemcpyDeviceToDevice, stream);
}